// Round 1
// baseline (707.229 us; speedup 1.0000x reference)
//
#include <hip/hip_runtime.h>

// ---- problem constants ----
// B=16, C=1024, H=W=64, nodes 32x32, N=1024, HID=16
// d_out float offsets
#define ZOFF   16777216   // z   (B*N*HID = 262144)
#define ZHOFF  17039360   // z_hat (262144)
#define KLOFF  17301504   // kl scalar
#define DLOFF  17301505   // dl (16)
// ws float offsets
#define AD_W   0          // Ad[B*N] = 16384
#define DIS_W  16384      // dis[B*N]
#define ACC_W  32768      // sigma[16], kl@+16, lsum@+17, gamma[16]@+18

// ---------------- K1: 2x2 mean pool: feature -> nodes (LA region scratch) ----
__global__ __launch_bounds__(256) void pool_kernel(const float* __restrict__ f,
                                                   float* __restrict__ nodes) {
    int t = blockIdx.x * 256 + threadIdx.x;   // 8,388,608 threads, 2 outputs each
    int x2 = t & 15;
    int y  = (t >> 4) & 31;
    int bc = t >> 9;                          // b*1024 + c
    const float4* src = (const float4*)f;
    int i4 = bc * 1024 + y * 32 + x2;         // float4 index of row 2y
    float4 r0 = src[i4];
    float4 r1 = src[i4 + 16];                 // row 2y+1
    float2 o;
    o.x = 0.25f * (r0.x + r0.y + r1.x + r1.y);
    o.y = 0.25f * (r0.z + r0.w + r1.z + r1.w);
    ((float2*)nodes)[bc * 512 + y * 16 + x2] = o;
}

// ---------------- K2: 3x3 SAME conv (mu) + 1x1 conv (log_var), fp32 ---------
// grid: 256 blocks = (b, ytile of 2 rows); block 256 thr = 64 pos x 4 o-groups
__global__ __launch_bounds__(256) void conv_kernel(
    const float* __restrict__ nodes, const float* __restrict__ mu_w,
    const float* __restrict__ mu_bias, const float* __restrict__ lv_w,
    const float* __restrict__ lv_bias, float* __restrict__ mu_out,
    float* __restrict__ lv_out)
{
    __shared__ float sn[8][4][34];            // 8 ch x 4 rows x (32+2 halo)
    int b  = blockIdx.x >> 4;
    int y0 = (blockIdx.x & 15) * 2;
    int t  = threadIdx.x;
    int py = (t >> 5) & 1;
    int px = t & 31;
    int ogu = __builtin_amdgcn_readfirstlane(t >> 6);  // wave-uniform o-group

    if (t < 64) sn[t >> 3][(t >> 1) & 3][(t & 1) * 33] = 0.0f;  // x halo zeros

    float accm[4] = {0.f, 0.f, 0.f, 0.f};
    float accv[4] = {0.f, 0.f, 0.f, 0.f};
    const float* nb = nodes + b * (1024 * 1024);

    for (int c0 = 0; c0 < 1024; c0 += 8) {
        __syncthreads();
        #pragma unroll
        for (int k = 0; k < 4; ++k) {         // stage 8ch x 4rows x 32cols
            int i = t + k * 256;
            int cl = i >> 7, rem = i & 127;
            int ry = rem >> 5, x = rem & 31;
            int r = y0 - 1 + ry;
            float v = 0.0f;
            if (r >= 0 && r < 32) v = nb[(c0 + cl) * 1024 + r * 32 + x];
            sn[cl][ry][1 + x] = v;
        }
        __syncthreads();
        #pragma unroll
        for (int cc = 0; cc < 8; ++cc) {
            int c = c0 + cc;
            float v00 = sn[cc][py][px],   v01 = sn[cc][py][px+1],   v02 = sn[cc][py][px+2];
            float v10 = sn[cc][py+1][px], v11 = sn[cc][py+1][px+1], v12 = sn[cc][py+1][px+2];
            float v20 = sn[cc][py+2][px], v21 = sn[cc][py+2][px+1], v22 = sn[cc][py+2][px+2];
            #pragma unroll
            for (int j = 0; j < 4; ++j) {
                const float* w = mu_w + (((ogu * 4 + j) << 10) + c) * 9;  // uniform -> s_load
                accm[j] += w[0]*v00 + w[1]*v01 + w[2]*v02
                         + w[3]*v10 + w[4]*v11 + w[5]*v12
                         + w[6]*v20 + w[7]*v21 + w[8]*v22;
                accv[j] += lv_w[((ogu * 4 + j) << 10) + c] * v11;
            }
        }
    }
    int pidx = (y0 + py) * 32 + px;
    #pragma unroll
    for (int j = 0; j < 4; ++j) {
        int o = ogu * 4 + j;
        mu_out[((b * 16 + o) << 10) + pidx] = accm[j] + mu_bias[o];
        lv_out[((b * 16 + o) << 10) + pidx] = accv[j] + lv_bias[o];
    }
}

// ---------------- K3a: per-node Ad, partial sigma/kl/logsum --------------
__global__ __launch_bounds__(256) void stats_kernel(const float* __restrict__ mu,
        const float* __restrict__ lv, float* __restrict__ ws)
{
    int t = blockIdx.x * 256 + threadIdx.x;   // 16384 nodes (b*1024+n)
    int b = t >> 10;
    const float4* m4 = (const float4*)mu + t * 4;
    const float4* l4 = (const float4*)lv + t * 4;
    float ad = 0.f, klp = 0.f;
    #pragma unroll
    for (int k = 0; k < 4; ++k) {
        float4 m = m4[k];
        float4 l = l4[k];
        float sq = m.x*m.x + m.y*m.y + m.z*m.z + m.w*m.w;
        ad  += sq;
        klp += 4.0f + 2.0f * (l.x + l.y + l.z + l.w) - sq
             - (expf(2.f*l.x) + expf(2.f*l.y) + expf(2.f*l.z) + expf(2.f*l.w));
    }
    ws[AD_W + t] = ad;
    float lg = logf(ad + 1e-7f);
    float sg = ad;
    #pragma unroll
    for (int off = 32; off > 0; off >>= 1) {
        sg  += __shfl_down(sg, off);
        klp += __shfl_down(klp, off);
        lg  += __shfl_down(lg, off);
    }
    if ((threadIdx.x & 63) == 0) {
        atomicAdd(&ws[ACC_W + b], sg);
        atomicAdd(&ws[ACC_W + 16], klp);
        atomicAdd(&ws[ACC_W + 17], lg);
    }
}

// ---------------- K3b: gamma, kl_loss, dl_loss ---------------------------
__global__ void finalize_kernel(float* __restrict__ ws, float* __restrict__ out) {
    int t = threadIdx.x;
    if (t < 16) {
        float sigma = ws[ACC_W + t];
        float g = sqrtf(1.0f + 1024.0f / (sigma + 1e-7f));
        ws[ACC_W + 18 + t] = g;
        out[DLOFF + t] = -g * ws[ACC_W + 17] / 16777216.0f;
        if (t == 0) out[KLOFF] = -0.5f * ws[ACC_W + 16];
    }
}

// ---------------- K3c: z_hat = gamma * mu * (1 - lv), in place over lv ---
__global__ __launch_bounds__(256) void zh_kernel(const float* __restrict__ mu,
        float* __restrict__ lvzh, const float* __restrict__ gamma)
{
    int i = blockIdx.x * 256 + threadIdx.x;   // 65536 float4
    int b = i >> 12;
    float g = gamma[b];
    float4 m = ((const float4*)mu)[i];
    float4 l = ((float4*)lvzh)[i];
    float4 zh;
    zh.x = g * m.x * (1.0f - l.x);
    zh.y = g * m.y * (1.0f - l.y);
    zh.z = g * m.z * (1.0f - l.z);
    zh.w = g * m.w * (1.0f - l.w);
    ((float4*)lvzh)[i] = zh;
}

// ---------------- K4: deg row sums -> dis = (deg+1e-5)^-0.5 --------------
// grid 256 = (b, ntile 64); block: 4 waves = 4 m-quarters x 64 n
__global__ __launch_bounds__(256) void deg_kernel(const float* __restrict__ z,
        float* __restrict__ ws)
{
    __shared__ float psum[4][64];
    int b  = blockIdx.x >> 4;
    int n0 = (blockIdx.x & 15) * 64;
    int t  = threadIdx.x;
    int ln = t & 63;
    int mq = __builtin_amdgcn_readfirstlane(t >> 6);
    const float* zb = z + (b << 14);
    const float4* a4 = (const float4*)(zb + (n0 + ln) * 16);
    float4 a0 = a4[0], a1 = a4[1], a2 = a4[2], a3 = a4[3];
    float rs = 0.f;
    const float* zm = zb + (mq << 12);
    for (int m = 0; m < 256; ++m) {
        const float4* s4 = (const float4*)(zm + m * 16);   // wave-uniform -> s_load
        float4 s0 = s4[0], s1 = s4[1], s2 = s4[2], s3 = s4[3];
        float d = a0.x*s0.x + a0.y*s0.y + a0.z*s0.z + a0.w*s0.w
                + a1.x*s1.x + a1.y*s1.y + a1.z*s1.z + a1.w*s1.w
                + a2.x*s2.x + a2.y*s2.y + a2.z*s2.z + a2.w*s2.w
                + a3.x*s3.x + a3.y*s3.y + a3.z*s3.z + a3.w*s3.w;
        rs += fmaxf(d, 0.f);
    }
    psum[mq][ln] = rs;
    __syncthreads();
    if (t < 64) {
        float total = psum[0][t] + psum[1][t] + psum[2][t] + psum[3][t];
        int n = n0 + t;
        float g = ws[ACC_W + 18 + b];
        float deg = total + g * ws[AD_W + (b << 10) + n] + 1.0f;
        ws[DIS_W + (b << 10) + n] = rsqrtf(deg + 1e-5f);
    }
}

// ---------------- K5: LA[b,n,m] = dis_n * dis_m * A ----------------------
// grid 4096 = (b, 64x64 tile); block 256: each thread 4x4 outputs
__global__ __launch_bounds__(256) void la_kernel(const float* __restrict__ z,
        const float* __restrict__ ws, float* __restrict__ LA)
{
    __shared__ float4 za[256];
    __shared__ float4 zbm[256];
    __shared__ float dan[64], dbm[64];
    int b    = blockIdx.x >> 8;
    int tile = blockIdx.x & 255;
    int n0 = (tile >> 4) * 64;
    int m0 = (tile & 15) * 64;
    int t  = threadIdx.x;
    const float4* zsrc = (const float4*)(z + (b << 14));
    za[t]  = zsrc[(n0 << 2) + t];
    zbm[t] = zsrc[(m0 << 2) + t];
    const float* dis = ws + DIS_W + (b << 10);
    if (t < 64)       dan[t]      = dis[n0 + t];
    else if (t < 128) dbm[t - 64] = dis[m0 + (t - 64)];
    __syncthreads();
    int ri = t >> 4;
    int cj = t & 15;
    float acc[4][4] = {{0.f, 0.f, 0.f, 0.f}, {0.f, 0.f, 0.f, 0.f},
                       {0.f, 0.f, 0.f, 0.f}, {0.f, 0.f, 0.f, 0.f}};
    #pragma unroll
    for (int kk = 0; kk < 4; ++kk) {
        float4 av[4], bv[4];
        #pragma unroll
        for (int i = 0; i < 4; ++i) av[i] = za[((ri * 4 + i) << 2) + kk];
        #pragma unroll
        for (int j = 0; j < 4; ++j) bv[j] = zbm[((cj * 4 + j) << 2) + kk];
        #pragma unroll
        for (int i = 0; i < 4; ++i)
            #pragma unroll
            for (int j = 0; j < 4; ++j)
                acc[i][j] += av[i].x * bv[j].x + av[i].y * bv[j].y
                           + av[i].z * bv[j].z + av[i].w * bv[j].w;
    }
    float g = ws[ACC_W + 18 + b];
    const float* Ad = ws + AD_W + (b << 10);
    #pragma unroll
    for (int i = 0; i < 4; ++i) {
        int n = n0 + ri * 4 + i;
        float dn = dan[ri * 4 + i];
        float4 o;
        float* op = &o.x;
        #pragma unroll
        for (int j = 0; j < 4; ++j) {
            int m = m0 + cj * 4 + j;
            float v = fmaxf(acc[i][j], 0.f);
            if (n == m) v += g * Ad[n] + 1.0f;
            op[j] = dn * dbm[cj * 4 + j] * v;
        }
        *(float4*)(LA + ((size_t)b << 20) + ((size_t)n << 10) + m0 + cj * 4) = o;
    }
}

extern "C" void kernel_launch(void* const* d_in, const int* in_sizes, int n_in,
                              void* d_out, int out_size, void* d_ws, size_t ws_size,
                              hipStream_t stream) {
    const float* feature = (const float*)d_in[0];
    const float* mu_w    = (const float*)d_in[1];
    const float* mu_b    = (const float*)d_in[2];
    const float* lv_w    = (const float*)d_in[3];
    const float* lv_b    = (const float*)d_in[4];
    float* out = (float*)d_out;
    float* ws  = (float*)d_ws;
    float* nodes = out;                       // LA region reused as pool scratch

    hipMemsetAsync(ws + ACC_W, 0, 64 * sizeof(float), stream);
    pool_kernel<<<32768, 256, 0, stream>>>(feature, nodes);
    // mu -> z slot (z IS mu flat); log_var -> z_hat slot (temp)
    conv_kernel<<<256, 256, 0, stream>>>(nodes, mu_w, mu_b, lv_w, lv_b,
                                         out + ZOFF, out + ZHOFF);
    stats_kernel<<<64, 256, 0, stream>>>(out + ZOFF, out + ZHOFF, ws);
    finalize_kernel<<<1, 64, 0, stream>>>(ws, out);
    zh_kernel<<<256, 256, 0, stream>>>(out + ZOFF, out + ZHOFF, ws + ACC_W + 18);
    deg_kernel<<<256, 256, 0, stream>>>(out + ZOFF, ws);
    la_kernel<<<4096, 256, 0, stream>>>(out + ZOFF, ws, out);
}

// Round 2
// 319.477 us; speedup vs baseline: 2.2137x; 2.2137x over previous
//
#include <hip/hip_runtime.h>

// ---- problem constants ----
// B=16, C=1024, H=W=64, nodes 32x32, N=1024, HID=16
// d_out float offsets
#define ZOFF   16777216   // z   (B*N*HID = 262144)  == mu flat
#define ZHOFF  17039360   // z_hat (262144)          == log_var temp, then z_hat
#define KLOFF  17301504   // kl scalar
#define DLOFF  17301505   // dl (16)
// ws float offsets
#define AD_W   0          // Ad[B*N] = 16384
#define DIS_W  16384      // dis[B*N]
#define ACC_W  32768      // sigma[16], kl@+16, lsum@+17, gamma[16]@+18

// ---------------- K1: 2x2 mean pool: feature -> nodes (LA region scratch) ----
__global__ __launch_bounds__(256) void pool_kernel(const float* __restrict__ f,
                                                   float* __restrict__ nodes) {
    int t = blockIdx.x * 256 + threadIdx.x;   // 8,388,608 threads, 2 outputs each
    int x2 = t & 15;
    int y  = (t >> 4) & 31;
    int bc = t >> 9;                          // b*1024 + c
    const float4* src = (const float4*)f;
    int i4 = bc * 1024 + y * 32 + x2;         // float4 index of row 2y
    float4 r0 = src[i4];
    float4 r1 = src[i4 + 16];                 // row 2y+1
    float2 o;
    o.x = 0.25f * (r0.x + r0.y + r1.x + r1.y);
    o.y = 0.25f * (r0.z + r0.w + r1.z + r1.w);
    ((float2*)nodes)[bc * 512 + y * 16 + x2] = o;
}

// ---------------- K2a: init mu/lv with biases (atomic accumulation target) --
__global__ __launch_bounds__(256) void init_kernel(const float* __restrict__ mu_b,
        const float* __restrict__ lv_b, float* __restrict__ mu_out,
        float* __restrict__ lv_out)
{
    int i = blockIdx.x * 256 + threadIdx.x;   // 131072 float4 per tensor
    int o = (i >> 8) & 15;                    // 256 float4 per (b,o) row
    float4 m = {mu_b[o], mu_b[o], mu_b[o], mu_b[o]};
    float4 l = {lv_b[o], lv_b[o], lv_b[o], lv_b[o]};
    ((float4*)mu_out)[i] = m;
    ((float4*)lv_out)[i] = l;
}

// ---------------- K2b: 3x3 SAME conv (mu) + 1x1 conv (lv), fp32 split-K ----
// grid 2048 = b(16) x ytile(16, 2 rows) x kchunk(8, 128 ch)
// block 256 thr = 64 pos (2 rows x 32 cols) x 4 o-groups
__global__ __launch_bounds__(256) void conv_kernel(
    const float* __restrict__ nodes, const float* __restrict__ mu_w,
    const float* __restrict__ lv_w, float* __restrict__ mu_out,
    float* __restrict__ lv_out)
{
    __shared__ float sn[8][4][34];            // 8 ch x 4 rows x (32+2 halo)
    int blk = blockIdx.x;
    int b   = blk >> 7;
    int y0  = ((blk >> 3) & 15) * 2;
    int cb  = (blk & 7) * 128;                // channel chunk base
    int t   = threadIdx.x;
    int py  = (t >> 5) & 1;
    int px  = t & 31;
    int ogu = __builtin_amdgcn_readfirstlane(t >> 6);  // wave-uniform o-group

    if (t < 64) sn[t >> 3][(t >> 1) & 3][(t & 1) * 33] = 0.0f;  // x halo zeros

    float accm[4] = {0.f, 0.f, 0.f, 0.f};
    float accv[4] = {0.f, 0.f, 0.f, 0.f};
    const float* nb = nodes + b * (1024 * 1024);

    for (int c0 = cb; c0 < cb + 128; c0 += 8) {
        __syncthreads();
        #pragma unroll
        for (int k = 0; k < 4; ++k) {         // stage 8ch x 4rows x 32cols
            int i = t + k * 256;
            int cl = i >> 7, rem = i & 127;
            int ry = rem >> 5, x = rem & 31;
            int r = y0 - 1 + ry;
            float v = 0.0f;
            if (r >= 0 && r < 32) v = nb[(c0 + cl) * 1024 + r * 32 + x];
            sn[cl][ry][1 + x] = v;
        }
        __syncthreads();
        #pragma unroll
        for (int cc = 0; cc < 8; ++cc) {
            int c = c0 + cc;
            float v00 = sn[cc][py][px],   v01 = sn[cc][py][px+1],   v02 = sn[cc][py][px+2];
            float v10 = sn[cc][py+1][px], v11 = sn[cc][py+1][px+1], v12 = sn[cc][py+1][px+2];
            float v20 = sn[cc][py+2][px], v21 = sn[cc][py+2][px+1], v22 = sn[cc][py+2][px+2];
            #pragma unroll
            for (int j = 0; j < 4; ++j) {
                const float* w = mu_w + (((ogu * 4 + j) << 10) + c) * 9;  // uniform -> s_load
                accm[j] += w[0]*v00 + w[1]*v01 + w[2]*v02
                         + w[3]*v10 + w[4]*v11 + w[5]*v12
                         + w[6]*v20 + w[7]*v21 + w[8]*v22;
                accv[j] += lv_w[((ogu * 4 + j) << 10) + c] * v11;
            }
        }
    }
    int pidx = (y0 + py) * 32 + px;
    #pragma unroll
    for (int j = 0; j < 4; ++j) {
        int o = ogu * 4 + j;
        atomicAdd(&mu_out[((b * 16 + o) << 10) + pidx], accm[j]);
        atomicAdd(&lv_out[((b * 16 + o) << 10) + pidx], accv[j]);
    }
}

// ---------------- K3a: per-node Ad, partial sigma/kl/logsum --------------
__global__ __launch_bounds__(256) void stats_kernel(const float* __restrict__ mu,
        const float* __restrict__ lv, float* __restrict__ ws)
{
    int t = blockIdx.x * 256 + threadIdx.x;   // 16384 nodes (b*1024+n)
    int b = t >> 10;
    const float4* m4 = (const float4*)mu + t * 4;
    const float4* l4 = (const float4*)lv + t * 4;
    float ad = 0.f, klp = 0.f;
    #pragma unroll
    for (int k = 0; k < 4; ++k) {
        float4 m = m4[k];
        float4 l = l4[k];
        float sq = m.x*m.x + m.y*m.y + m.z*m.z + m.w*m.w;
        ad  += sq;
        klp += 4.0f + 2.0f * (l.x + l.y + l.z + l.w) - sq
             - (expf(2.f*l.x) + expf(2.f*l.y) + expf(2.f*l.z) + expf(2.f*l.w));
    }
    ws[AD_W + t] = ad;
    float lg = logf(ad + 1e-7f);
    float sg = ad;
    #pragma unroll
    for (int off = 32; off > 0; off >>= 1) {
        sg  += __shfl_down(sg, off);
        klp += __shfl_down(klp, off);
        lg  += __shfl_down(lg, off);
    }
    if ((threadIdx.x & 63) == 0) {
        atomicAdd(&ws[ACC_W + b], sg);
        atomicAdd(&ws[ACC_W + 16], klp);
        atomicAdd(&ws[ACC_W + 17], lg);
    }
}

// ---------------- K3b: gamma, kl_loss, dl_loss ---------------------------
__global__ void finalize_kernel(float* __restrict__ ws, float* __restrict__ out) {
    int t = threadIdx.x;
    if (t < 16) {
        float sigma = ws[ACC_W + t];
        float g = sqrtf(1.0f + 1024.0f / (sigma + 1e-7f));
        ws[ACC_W + 18 + t] = g;
        out[DLOFF + t] = -g * ws[ACC_W + 17] / 16777216.0f;
        if (t == 0) out[KLOFF] = -0.5f * ws[ACC_W + 16];
    }
}

// ---------------- K3c: z_hat = gamma * mu * (1 - lv), in place over lv ---
__global__ __launch_bounds__(256) void zh_kernel(const float* __restrict__ mu,
        float* __restrict__ lvzh, const float* __restrict__ gamma)
{
    int i = blockIdx.x * 256 + threadIdx.x;   // 65536 float4
    int b = i >> 12;
    float g = gamma[b];
    float4 m = ((const float4*)mu)[i];
    float4 l = ((float4*)lvzh)[i];
    float4 zh;
    zh.x = g * m.x * (1.0f - l.x);
    zh.y = g * m.y * (1.0f - l.y);
    zh.z = g * m.z * (1.0f - l.z);
    zh.w = g * m.w * (1.0f - l.w);
    ((float4*)lvzh)[i] = zh;
}

// ---------------- K4: deg row sums -> dis = (deg+1e-5)^-0.5 --------------
// grid 1024 = b(16) x ntile(64, 16 n each); block 256 = 16 n x 16 m-groups
__global__ __launch_bounds__(256) void deg_kernel(const float* __restrict__ z,
        float* __restrict__ ws)
{
    __shared__ float psum[16][17];
    int b  = blockIdx.x >> 6;
    int n0 = (blockIdx.x & 63) * 16;
    int t  = threadIdx.x;
    int nl = t & 15;
    int g  = t >> 4;                          // m-group, 64 m each
    const float* zb = z + (b << 14);
    const float4* a4 = (const float4*)(zb + (n0 + nl) * 16);
    float4 a0 = a4[0], a1 = a4[1], a2 = a4[2], a3 = a4[3];
    float rs = 0.f;
    const float4* m4 = (const float4*)(zb + (g << 6) * 16);
    for (int m = 0; m < 64; ++m) {
        float4 s0 = m4[m*4], s1 = m4[m*4+1], s2 = m4[m*4+2], s3 = m4[m*4+3];
        float d = a0.x*s0.x + a0.y*s0.y + a0.z*s0.z + a0.w*s0.w
                + a1.x*s1.x + a1.y*s1.y + a1.z*s1.z + a1.w*s1.w
                + a2.x*s2.x + a2.y*s2.y + a2.z*s2.z + a2.w*s2.w
                + a3.x*s3.x + a3.y*s3.y + a3.z*s3.z + a3.w*s3.w;
        rs += fmaxf(d, 0.f);
    }
    psum[g][nl] = rs;
    __syncthreads();
    if (t < 16) {
        float total = 0.f;
        #pragma unroll
        for (int gg = 0; gg < 16; ++gg) total += psum[gg][t];
        int n = n0 + t;
        float gam = ws[ACC_W + 18 + b];
        float deg = total + gam * ws[AD_W + (b << 10) + n] + 1.0f;
        ws[DIS_W + (b << 10) + n] = rsqrtf(deg + 1e-5f);
    }
}

// ---------------- K5: LA[b,n,m] = dis_n * dis_m * A ----------------------
// grid 4096 = (b, 64x64 tile); block 256: each thread 4x4 outputs
__global__ __launch_bounds__(256) void la_kernel(const float* __restrict__ z,
        const float* __restrict__ ws, float* __restrict__ LA)
{
    __shared__ float4 za[256];
    __shared__ float4 zbm[256];
    __shared__ float dan[64], dbm[64];
    int b    = blockIdx.x >> 8;
    int tile = blockIdx.x & 255;
    int n0 = (tile >> 4) * 64;
    int m0 = (tile & 15) * 64;
    int t  = threadIdx.x;
    const float4* zsrc = (const float4*)(z + (b << 14));
    za[t]  = zsrc[(n0 << 2) + t];
    zbm[t] = zsrc[(m0 << 2) + t];
    const float* dis = ws + DIS_W + (b << 10);
    if (t < 64)       dan[t]      = dis[n0 + t];
    else if (t < 128) dbm[t - 64] = dis[m0 + (t - 64)];
    __syncthreads();
    int ri = t >> 4;
    int cj = t & 15;
    float acc[4][4] = {{0.f, 0.f, 0.f, 0.f}, {0.f, 0.f, 0.f, 0.f},
                       {0.f, 0.f, 0.f, 0.f}, {0.f, 0.f, 0.f, 0.f}};
    #pragma unroll
    for (int kk = 0; kk < 4; ++kk) {
        float4 av[4], bv[4];
        #pragma unroll
        for (int i = 0; i < 4; ++i) av[i] = za[((ri * 4 + i) << 2) + kk];
        #pragma unroll
        for (int j = 0; j < 4; ++j) bv[j] = zbm[((cj * 4 + j) << 2) + kk];
        #pragma unroll
        for (int i = 0; i < 4; ++i)
            #pragma unroll
            for (int j = 0; j < 4; ++j)
                acc[i][j] += av[i].x * bv[j].x + av[i].y * bv[j].y
                           + av[i].z * bv[j].z + av[i].w * bv[j].w;
    }
    float g = ws[ACC_W + 18 + b];
    const float* Ad = ws + AD_W + (b << 10);
    #pragma unroll
    for (int i = 0; i < 4; ++i) {
        int n = n0 + ri * 4 + i;
        float dn = dan[ri * 4 + i];
        float4 o;
        float* op = &o.x;
        #pragma unroll
        for (int j = 0; j < 4; ++j) {
            int m = m0 + cj * 4 + j;
            float v = fmaxf(acc[i][j], 0.f);
            if (n == m) v += g * Ad[n] + 1.0f;
            op[j] = dn * dbm[cj * 4 + j] * v;
        }
        *(float4*)(LA + ((size_t)b << 20) + ((size_t)n << 10) + m0 + cj * 4) = o;
    }
}

extern "C" void kernel_launch(void* const* d_in, const int* in_sizes, int n_in,
                              void* d_out, int out_size, void* d_ws, size_t ws_size,
                              hipStream_t stream) {
    const float* feature = (const float*)d_in[0];
    const float* mu_w    = (const float*)d_in[1];
    const float* mu_b    = (const float*)d_in[2];
    const float* lv_w    = (const float*)d_in[3];
    const float* lv_b    = (const float*)d_in[4];
    float* out = (float*)d_out;
    float* ws  = (float*)d_ws;
    float* nodes = out;                       // LA region reused as pool scratch

    hipMemsetAsync(ws + ACC_W, 0, 64 * sizeof(float), stream);
    pool_kernel<<<32768, 256, 0, stream>>>(feature, nodes);
    // mu -> z slot (z IS mu flat); log_var -> z_hat slot (temp)
    init_kernel<<<512, 256, 0, stream>>>(mu_b, lv_b, out + ZOFF, out + ZHOFF);
    conv_kernel<<<2048, 256, 0, stream>>>(nodes, mu_w, lv_w, out + ZOFF, out + ZHOFF);
    stats_kernel<<<64, 256, 0, stream>>>(out + ZOFF, out + ZHOFF, ws);
    finalize_kernel<<<1, 64, 0, stream>>>(ws, out);
    zh_kernel<<<256, 256, 0, stream>>>(out + ZOFF, out + ZHOFF, ws + ACC_W + 18);
    deg_kernel<<<1024, 256, 0, stream>>>(out + ZOFF, ws);
    la_kernel<<<4096, 256, 0, stream>>>(out + ZOFF, ws, out);
}

// Round 3
// 215.883 us; speedup vs baseline: 3.2760x; 1.4799x over previous
//
#include <hip/hip_runtime.h>

typedef short short8 __attribute__((ext_vector_type(8)));
typedef float f32x4 __attribute__((ext_vector_type(4)));

// ---- problem constants ----
// B=16, C=1024, H=W=64, nodes 32x32, N=1024, HID=16
// d_out float offsets
#define ZOFF   16777216   // z   (B*N*HID = 262144)  == mu flat
#define ZHOFF  17039360   // z_hat (262144)          == log_var temp, then z_hat
#define KLOFF  17301504   // kl scalar
#define DLOFF  17301505   // dl (16)
// d_out ushort offsets (scratch inside LA region, dead before la_kernel)
#define NT_U   0          // nodesT bf16 [16][1024][1024] = 16,777,216 ushorts
#define APK_U  16777216   // Apk bf16 [9][32][64][8] = 147,456
#define LVPK_U 16924672   // lvpk bf16 [32][64][8] = 16,384
// ws float offsets
#define AD_W   0          // Ad[B*N] = 16384
#define DIS_W  16384      // dis[B*N]
#define ACC_W  32768      // sigma[16], kl@+16, lsum@+17, gamma[16]@+18

__device__ __forceinline__ unsigned short f2bf(float f) {
    unsigned int u = __float_as_uint(f);
    unsigned int r = (u + 0x7fffu + ((u >> 16) & 1u)) >> 16;
    return (unsigned short)r;
}

// ---- K1: fused 2x2 mean pool + transpose: feature fp32 -> nodesT bf16 [b][p][c]
// grid 8192 = b(16) x y(32) x cblk(16 of 64ch); block 256
__global__ __launch_bounds__(256) void pool_tr_kernel(const float* __restrict__ f,
        unsigned short* __restrict__ nT)
{
    __shared__ float pl[64][35];
    int blk = blockIdx.x;
    int b  = blk >> 9;
    int y  = (blk >> 4) & 31;
    int cb = blk & 15;
    int t  = threadIdx.x;
    int cl = t >> 2, q2 = t & 3;
    int c  = (cb << 6) + cl;
    float acc[8] = {0.f,0.f,0.f,0.f,0.f,0.f,0.f,0.f};
    #pragma unroll
    for (int rr = 0; rr < 2; ++rr) {
        const float4* src = (const float4*)f
            + ((((b << 10) + c) << 6) + (y << 1) + rr) * 16 + (q2 << 2);
        #pragma unroll
        for (int m = 0; m < 4; ++m) {
            float4 v = src[m];
            acc[2*m]   += v.x + v.y;
            acc[2*m+1] += v.z + v.w;
        }
    }
    #pragma unroll
    for (int i = 0; i < 8; ++i) pl[cl][(q2 << 3) + i] = 0.25f * acc[i];
    __syncthreads();
    int px = t >> 3, cj = (t & 7) << 3;
    unsigned short o8[8];
    #pragma unroll
    for (int i = 0; i < 8; ++i) o8[i] = f2bf(pl[cj + i][px]);
    int ofs = (((b << 10) + (y << 5) + px) << 10) + (cb << 6) + cj;
    *(short8*)&nT[ofs] = *(short8*)o8;
}

// ---- K2a: repack weights to bf16 MFMA B-fragment order ----
__global__ __launch_bounds__(256) void prep_kernel(const float* __restrict__ mu_w,
        const float* __restrict__ lv_w, unsigned short* __restrict__ apk,
        unsigned short* __restrict__ lvpk)
{
    int idx = blockIdx.x * 256 + threadIdx.x;
    if (idx < 147456) {
        int tap = idx >> 14;
        int rem = idx & 16383;
        int ks = rem >> 9;
        int lane = (rem >> 3) & 63;
        int j = idx & 7;
        int o = lane & 15;
        int cc = (ks << 5) + ((lane >> 4) << 3) + j;
        apk[idx] = f2bf(mu_w[((o << 10) + cc) * 9 + tap]);
    } else if (idx < 163840) {
        int i2 = idx - 147456;
        int ks = i2 >> 9;
        int lane = (i2 >> 3) & 63;
        int j = i2 & 7;
        int o = lane & 15;
        int cc = (ks << 5) + ((lane >> 4) << 3) + j;
        lvpk[i2] = f2bf(lv_w[(o << 10) + cc]);
    }
}

// ---- K2b: init mu/lv with biases (atomic accumulation target) ----
__global__ __launch_bounds__(256) void init_kernel(const float* __restrict__ mu_b,
        const float* __restrict__ lv_b, float* __restrict__ mu_out,
        float* __restrict__ lv_out)
{
    int i = blockIdx.x * 256 + threadIdx.x;
    int o = (i >> 8) & 15;
    float4 m = {mu_b[o], mu_b[o], mu_b[o], mu_b[o]};
    float4 l = {lv_b[o], lv_b[o], lv_b[o], lv_b[o]};
    ((float4*)mu_out)[i] = m;
    ((float4*)lv_out)[i] = l;
}

// ---- K2c: MFMA conv: mu (3x3 SAME) + lv (1x1), bf16 in / fp32 atomic out ----
// grid 2048 = b(16) x ytile(16: 2 rows) x kchunk(8: 128 ch); block 256 = 4 waves
// wave w: y-row ry=w>>1, x-half xb=(w&1)*16. D[m=pos][n=o].
__global__ __launch_bounds__(256) void conv_mfma(const unsigned short* __restrict__ nT,
        const unsigned short* __restrict__ apk, const unsigned short* __restrict__ lvpk,
        float* __restrict__ mu_out, float* __restrict__ lv_out)
{
    __shared__ unsigned short st[4 * 34 * 32];   // [row 4][xx 34][ch 32] bf16, 8704B
    int blk = blockIdx.x;
    int b  = blk >> 7;
    int yt = (blk >> 3) & 15;
    int kc = blk & 7;
    int y0 = yt << 1;
    int t  = threadIdx.x;
    int w  = t >> 6, l = t & 63;
    int ry = w >> 1, xb = (w & 1) << 4;
    int px = l & 15, chg = l >> 4;
    f32x4 accm = {0.f, 0.f, 0.f, 0.f};
    f32x4 accv = {0.f, 0.f, 0.f, 0.f};

    if (t < 32) {                                 // static x-halo zeros (once)
        int row = t >> 3, side = (t >> 2) & 1, quarter = t & 3;
        short8 z8 = {0,0,0,0,0,0,0,0};
        *(short8*)&st[(row * 34 + side * 33) * 32 + quarter * 8] = z8;
    }

    for (int s = 0; s < 4; ++s) {
        int ksg = (kc << 2) + s;                  // global k-step 0..31
        int cs  = ksg << 5;                       // channel base
        __syncthreads();
        #pragma unroll
        for (int k2 = 0; k2 < 2; ++k2) {          // stage 4rows x 32x x 32ch
            int q = t + (k2 << 8);
            int e = q >> 2, quarter = q & 3;
            int row = e >> 5, x = e & 31;
            int yin = y0 - 1 + row;
            short8 v = {0,0,0,0,0,0,0,0};
            if (yin >= 0 && yin < 32)
                v = *(const short8*)&nT[(((b << 10) + (yin << 5) + x) << 10) + cs + quarter * 8];
            *(short8*)&st[(row * 34 + x + 1) * 32 + quarter * 8] = v;
        }
        __syncthreads();
        short8 a[3][3];
        #pragma unroll
        for (int ky = 0; ky < 3; ++ky) {
            int row = ry + ky;
            #pragma unroll
            for (int kx = 0; kx < 3; ++kx) {
                int xx = xb + px + kx;
                a[ky][kx] = *(const short8*)&st[(row * 34 + xx) * 32 + chg * 8];
            }
        }
        #pragma unroll
        for (int ky = 0; ky < 3; ++ky)
            #pragma unroll
            for (int kx = 0; kx < 3; ++kx) {
                int tap = ky * 3 + kx;
                short8 bw = *(const short8*)&apk[((tap << 5) + ksg) * 512 + l * 8];
                accm = __builtin_amdgcn_mfma_f32_16x16x32_bf16(a[ky][kx], bw, accm, 0, 0, 0);
            }
        short8 bv = *(const short8*)&lvpk[(ksg << 9) + l * 8];
        accv = __builtin_amdgcn_mfma_f32_16x16x32_bf16(a[1][1], bv, accv, 0, 0, 0);
    }
    // D: lane holds D[pos=(l>>4)*4+j][o=l&15]
    int o = px;
    int x = xb + (chg << 2);
    int base = (((b << 4) + o) << 10) + ((y0 + ry) << 5) + x;
    #pragma unroll
    for (int j = 0; j < 4; ++j) {
        atomicAdd(&mu_out[base + j], accm[j]);
        atomicAdd(&lv_out[base + j], accv[j]);
    }
}

// ---- K3a: per-node Ad, partial sigma/kl/logsum ----
__global__ __launch_bounds__(256) void stats_kernel(const float* __restrict__ mu,
        const float* __restrict__ lv, float* __restrict__ ws)
{
    int t = blockIdx.x * 256 + threadIdx.x;
    int b = t >> 10;
    const float4* m4 = (const float4*)mu + t * 4;
    const float4* l4 = (const float4*)lv + t * 4;
    float ad = 0.f, klp = 0.f;
    #pragma unroll
    for (int k = 0; k < 4; ++k) {
        float4 m = m4[k];
        float4 l = l4[k];
        float sq = m.x*m.x + m.y*m.y + m.z*m.z + m.w*m.w;
        ad  += sq;
        klp += 4.0f + 2.0f * (l.x + l.y + l.z + l.w) - sq
             - (expf(2.f*l.x) + expf(2.f*l.y) + expf(2.f*l.z) + expf(2.f*l.w));
    }
    ws[AD_W + t] = ad;
    float lg = logf(ad + 1e-7f);
    float sg = ad;
    #pragma unroll
    for (int off = 32; off > 0; off >>= 1) {
        sg  += __shfl_down(sg, off);
        klp += __shfl_down(klp, off);
        lg  += __shfl_down(lg, off);
    }
    if ((threadIdx.x & 63) == 0) {
        atomicAdd(&ws[ACC_W + b], sg);
        atomicAdd(&ws[ACC_W + 16], klp);
        atomicAdd(&ws[ACC_W + 17], lg);
    }
}

// ---- K3b: gamma, kl_loss, dl_loss ----
__global__ void finalize_kernel(float* __restrict__ ws, float* __restrict__ out) {
    int t = threadIdx.x;
    if (t < 16) {
        float sigma = ws[ACC_W + t];
        float g = sqrtf(1.0f + 1024.0f / (sigma + 1e-7f));
        ws[ACC_W + 18 + t] = g;
        out[DLOFF + t] = -g * ws[ACC_W + 17] / 16777216.0f;
        if (t == 0) out[KLOFF] = -0.5f * ws[ACC_W + 16];
    }
}

// ---- K3c: z_hat = gamma * mu * (1 - lv), in place over lv ----
__global__ __launch_bounds__(256) void zh_kernel(const float* __restrict__ mu,
        float* __restrict__ lvzh, const float* __restrict__ gamma)
{
    int i = blockIdx.x * 256 + threadIdx.x;
    int b = i >> 12;
    float g = gamma[b];
    float4 m = ((const float4*)mu)[i];
    float4 l = ((float4*)lvzh)[i];
    float4 zh;
    zh.x = g * m.x * (1.0f - l.x);
    zh.y = g * m.y * (1.0f - l.y);
    zh.z = g * m.z * (1.0f - l.z);
    zh.w = g * m.w * (1.0f - l.w);
    ((float4*)lvzh)[i] = zh;
}

// ---- K4: deg row sums -> dis ----
__global__ __launch_bounds__(256) void deg_kernel(const float* __restrict__ z,
        float* __restrict__ ws)
{
    __shared__ float psum[16][17];
    int b  = blockIdx.x >> 6;
    int n0 = (blockIdx.x & 63) * 16;
    int t  = threadIdx.x;
    int nl = t & 15;
    int g  = t >> 4;
    const float* zb = z + (b << 14);
    const float4* a4 = (const float4*)(zb + (n0 + nl) * 16);
    float4 a0 = a4[0], a1 = a4[1], a2 = a4[2], a3 = a4[3];
    float rs = 0.f;
    const float4* m4 = (const float4*)(zb + (g << 6) * 16);
    for (int m = 0; m < 64; ++m) {
        float4 s0 = m4[m*4], s1 = m4[m*4+1], s2 = m4[m*4+2], s3 = m4[m*4+3];
        float d = a0.x*s0.x + a0.y*s0.y + a0.z*s0.z + a0.w*s0.w
                + a1.x*s1.x + a1.y*s1.y + a1.z*s1.z + a1.w*s1.w
                + a2.x*s2.x + a2.y*s2.y + a2.z*s2.z + a2.w*s2.w
                + a3.x*s3.x + a3.y*s3.y + a3.z*s3.z + a3.w*s3.w;
        rs += fmaxf(d, 0.f);
    }
    psum[g][nl] = rs;
    __syncthreads();
    if (t < 16) {
        float total = 0.f;
        #pragma unroll
        for (int gg = 0; gg < 16; ++gg) total += psum[gg][t];
        int n = n0 + t;
        float gam = ws[ACC_W + 18 + b];
        float deg = total + gam * ws[AD_W + (b << 10) + n] + 1.0f;
        ws[DIS_W + (b << 10) + n] = rsqrtf(deg + 1e-5f);
    }
}

// ---- K5: LA[b,n,m] = dis_n * dis_m * A ----
__global__ __launch_bounds__(256) void la_kernel(const float* __restrict__ z,
        const float* __restrict__ ws, float* __restrict__ LA)
{
    __shared__ float4 za[256];
    __shared__ float4 zbm[256];
    __shared__ float dan[64], dbm[64];
    int b    = blockIdx.x >> 8;
    int tile = blockIdx.x & 255;
    int n0 = (tile >> 4) * 64;
    int m0 = (tile & 15) * 64;
    int t  = threadIdx.x;
    const float4* zsrc = (const float4*)(z + (b << 14));
    za[t]  = zsrc[(n0 << 2) + t];
    zbm[t] = zsrc[(m0 << 2) + t];
    const float* dis = ws + DIS_W + (b << 10);
    if (t < 64)       dan[t]      = dis[n0 + t];
    else if (t < 128) dbm[t - 64] = dis[m0 + (t - 64)];
    __syncthreads();
    int ri = t >> 4;
    int cj = t & 15;
    float acc[4][4] = {{0.f,0.f,0.f,0.f},{0.f,0.f,0.f,0.f},
                       {0.f,0.f,0.f,0.f},{0.f,0.f,0.f,0.f}};
    #pragma unroll
    for (int kk = 0; kk < 4; ++kk) {
        float4 av[4], bv[4];
        #pragma unroll
        for (int i = 0; i < 4; ++i) av[i] = za[((ri * 4 + i) << 2) + kk];
        #pragma unroll
        for (int j = 0; j < 4; ++j) bv[j] = zbm[((cj * 4 + j) << 2) + kk];
        #pragma unroll
        for (int i = 0; i < 4; ++i)
            #pragma unroll
            for (int j = 0; j < 4; ++j)
                acc[i][j] += av[i].x * bv[j].x + av[i].y * bv[j].y
                           + av[i].z * bv[j].z + av[i].w * bv[j].w;
    }
    float g = ws[ACC_W + 18 + b];
    const float* Ad = ws + AD_W + (b << 10);
    #pragma unroll
    for (int i = 0; i < 4; ++i) {
        int n = n0 + ri * 4 + i;
        float dn = dan[ri * 4 + i];
        float4 o;
        float* op = &o.x;
        #pragma unroll
        for (int j = 0; j < 4; ++j) {
            int m = m0 + cj * 4 + j;
            float v = fmaxf(acc[i][j], 0.f);
            if (n == m) v += g * Ad[n] + 1.0f;
            op[j] = dn * dbm[cj * 4 + j] * v;
        }
        *(float4*)(LA + ((size_t)b << 20) + ((size_t)n << 10) + m0 + cj * 4) = o;
    }
}

extern "C" void kernel_launch(void* const* d_in, const int* in_sizes, int n_in,
                              void* d_out, int out_size, void* d_ws, size_t ws_size,
                              hipStream_t stream) {
    const float* feature = (const float*)d_in[0];
    const float* mu_w    = (const float*)d_in[1];
    const float* mu_b    = (const float*)d_in[2];
    const float* lv_w    = (const float*)d_in[3];
    const float* lv_b    = (const float*)d_in[4];
    float* out = (float*)d_out;
    float* ws  = (float*)d_ws;
    unsigned short* nT   = (unsigned short*)d_out;          // LA region scratch
    unsigned short* apk  = nT + APK_U;
    unsigned short* lvpk = nT + LVPK_U;

    hipMemsetAsync(ws + ACC_W, 0, 64 * sizeof(float), stream);
    pool_tr_kernel<<<8192, 256, 0, stream>>>(feature, nT);
    prep_kernel<<<640, 256, 0, stream>>>(mu_w, lv_w, apk, lvpk);
    init_kernel<<<512, 256, 0, stream>>>(mu_b, lv_b, out + ZOFF, out + ZHOFF);
    conv_mfma<<<2048, 256, 0, stream>>>(nT, apk, lvpk, out + ZOFF, out + ZHOFF);
    stats_kernel<<<64, 256, 0, stream>>>(out + ZOFF, out + ZHOFF, ws);
    finalize_kernel<<<1, 64, 0, stream>>>(ws, out);
    zh_kernel<<<256, 256, 0, stream>>>(out + ZOFF, out + ZHOFF, ws + ACC_W + 18);
    deg_kernel<<<1024, 256, 0, stream>>>(out + ZOFF, ws);
    la_kernel<<<4096, 256, 0, stream>>>(out + ZOFF, ws, out);
}

// Round 4
// 168.497 us; speedup vs baseline: 4.1973x; 1.2812x over previous
//
#include <hip/hip_runtime.h>

typedef short short8 __attribute__((ext_vector_type(8)));
typedef float f32x4 __attribute__((ext_vector_type(4)));

// ---- problem constants ----
// B=16, C=1024, H=W=64, nodes 32x32, N=1024, HID=16
// d_out float offsets
#define ZOFF   16777216   // z   (B*N*HID = 262144)  == mu flat (with bias)
#define ZHOFF  17039360   // z_hat (262144)          == log_var temp, then z_hat
#define KLOFF  17301504   // kl scalar
#define DLOFF  17301505   // dl (16)
// d_out ushort offsets (scratch inside LA region, dead before la_kernel)
#define NT_U   0          // nodesT bf16 [16][1024][1024] = 16,777,216 ushorts
#define APK_U  16777216   // Apk bf16 [9][32][64][8] = 147,456
#define LVPK_U 16924672   // lvpk bf16 [32][64][8] = 16,384
// ws float offsets
#define AD_W   0          // Ad[B*N] = 16384
#define DIS_W  16384      // dis[B*N]
#define PART_W 32768      // 64 blocks x 4 floats: sigma,kl,lg partials
#define GAM_W  33024      // gamma[16]
#define PMU_W  65536      // mu partials [8][16][16][1024] = 2,097,152 floats
#define PLV_W  2162688    // lv partials, same shape

__device__ __forceinline__ unsigned short f2bf(float f) {
    unsigned int u = __float_as_uint(f);
    unsigned int r = (u + 0x7fffu + ((u >> 16) & 1u)) >> 16;
    return (unsigned short)r;
}

// ---- K1: fused 2x2 mean pool + transpose: feature fp32 -> nodesT bf16 [b][p][c]
__global__ __launch_bounds__(256) void pool_tr_kernel(const float* __restrict__ f,
        unsigned short* __restrict__ nT)
{
    __shared__ float pl[64][35];
    int blk = blockIdx.x;
    int b  = blk >> 9;
    int y  = (blk >> 4) & 31;
    int cb = blk & 15;
    int t  = threadIdx.x;
    int cl = t >> 2, q2 = t & 3;
    int c  = (cb << 6) + cl;
    float acc[8] = {0.f,0.f,0.f,0.f,0.f,0.f,0.f,0.f};
    #pragma unroll
    for (int rr = 0; rr < 2; ++rr) {
        const float4* src = (const float4*)f
            + ((((b << 10) + c) << 6) + (y << 1) + rr) * 16 + (q2 << 2);
        #pragma unroll
        for (int m = 0; m < 4; ++m) {
            float4 v = src[m];
            acc[2*m]   += v.x + v.y;
            acc[2*m+1] += v.z + v.w;
        }
    }
    #pragma unroll
    for (int i = 0; i < 8; ++i) pl[cl][(q2 << 3) + i] = 0.25f * acc[i];
    __syncthreads();
    int px = t >> 3, cj = (t & 7) << 3;
    unsigned short o8[8];
    #pragma unroll
    for (int i = 0; i < 8; ++i) o8[i] = f2bf(pl[cj + i][px]);
    int ofs = (((b << 10) + (y << 5) + px) << 10) + (cb << 6) + cj;
    *(short8*)&nT[ofs] = *(short8*)o8;
}

// ---- K2a: repack weights to bf16 MFMA B-fragment order ----
__global__ __launch_bounds__(256) void prep_kernel(const float* __restrict__ mu_w,
        const float* __restrict__ lv_w, unsigned short* __restrict__ apk,
        unsigned short* __restrict__ lvpk)
{
    int idx = blockIdx.x * 256 + threadIdx.x;
    if (idx < 147456) {
        int tap = idx >> 14;
        int rem = idx & 16383;
        int ks = rem >> 9;
        int lane = (rem >> 3) & 63;
        int j = idx & 7;
        int o = lane & 15;
        int cc = (ks << 5) + ((lane >> 4) << 3) + j;
        apk[idx] = f2bf(mu_w[((o << 10) + cc) * 9 + tap]);
    } else if (idx < 163840) {
        int i2 = idx - 147456;
        int ks = i2 >> 9;
        int lane = (i2 >> 3) & 63;
        int j = i2 & 7;
        int o = lane & 15;
        int cc = (ks << 5) + ((lane >> 4) << 3) + j;
        lvpk[i2] = f2bf(lv_w[(o << 10) + cc]);
    }
}

// ---- K2b: MFMA conv split-K partials: mu (3x3 SAME) + lv (1x1) --------------
// grid 2048 = b(16) x ytile(16: 2 rows) x kchunk(8: 128 ch); block 256 = 4 waves
__global__ __launch_bounds__(256) void conv_mfma(const unsigned short* __restrict__ nT,
        const unsigned short* __restrict__ apk, const unsigned short* __restrict__ lvpk,
        float* __restrict__ pmu, float* __restrict__ plv)
{
    __shared__ unsigned short st[4 * 34 * 32];   // [row 4][xx 34][ch 32] bf16
    int blk = blockIdx.x;
    int b  = blk >> 7;
    int yt = (blk >> 3) & 15;
    int kc = blk & 7;
    int y0 = yt << 1;
    int t  = threadIdx.x;
    int w  = t >> 6, l = t & 63;
    int ry = w >> 1, xb = (w & 1) << 4;
    int px = l & 15, chg = l >> 4;
    f32x4 accm = {0.f, 0.f, 0.f, 0.f};
    f32x4 accv = {0.f, 0.f, 0.f, 0.f};

    if (t < 32) {                                 // static x-halo zeros (once)
        int row = t >> 3, side = (t >> 2) & 1, quarter = t & 3;
        short8 z8 = {0,0,0,0,0,0,0,0};
        *(short8*)&st[(row * 34 + side * 33) * 32 + quarter * 8] = z8;
    }

    for (int s = 0; s < 4; ++s) {
        int ksg = (kc << 2) + s;                  // global k-step 0..31
        int cs  = ksg << 5;
        __syncthreads();
        #pragma unroll
        for (int k2 = 0; k2 < 2; ++k2) {
            int q = t + (k2 << 8);
            int e = q >> 2, quarter = q & 3;
            int row = e >> 5, x = e & 31;
            int yin = y0 - 1 + row;
            short8 v = {0,0,0,0,0,0,0,0};
            if (yin >= 0 && yin < 32)
                v = *(const short8*)&nT[(((b << 10) + (yin << 5) + x) << 10) + cs + quarter * 8];
            *(short8*)&st[(row * 34 + x + 1) * 32 + quarter * 8] = v;
        }
        __syncthreads();
        short8 a[3][3];
        #pragma unroll
        for (int ky = 0; ky < 3; ++ky) {
            int row = ry + ky;
            #pragma unroll
            for (int kx = 0; kx < 3; ++kx) {
                int xx = xb + px + kx;
                a[ky][kx] = *(const short8*)&st[(row * 34 + xx) * 32 + chg * 8];
            }
        }
        #pragma unroll
        for (int ky = 0; ky < 3; ++ky)
            #pragma unroll
            for (int kx = 0; kx < 3; ++kx) {
                int tap = ky * 3 + kx;
                short8 bw = *(const short8*)&apk[((tap << 5) + ksg) * 512 + l * 8];
                accm = __builtin_amdgcn_mfma_f32_16x16x32_bf16(a[ky][kx], bw, accm, 0, 0, 0);
            }
        short8 bv = *(const short8*)&lvpk[(ksg << 9) + l * 8];
        accv = __builtin_amdgcn_mfma_f32_16x16x32_bf16(a[1][1], bv, accv, 0, 0, 0);
    }
    // D: lane holds D[pos=(l>>4)*4+j][o=l&15]; plain stores to split-K partials
    int o = px;
    int x = xb + (chg << 2);
    int idx = (((kc << 4) + b) << 14) + (o << 10) + ((y0 + ry) << 5) + x;
    *(f32x4*)&pmu[idx] = accm;
    *(f32x4*)&plv[idx] = accv;
}

// ---- K3a: combine split-K + bias -> z/lv outputs; Ad, block partials -------
__global__ __launch_bounds__(256) void stats_kernel(const float* __restrict__ pmu,
        const float* __restrict__ plv, const float* __restrict__ mu_b,
        const float* __restrict__ lv_b, float* __restrict__ z,
        float* __restrict__ lvout, float* __restrict__ ws)
{
    int t = blockIdx.x * 256 + threadIdx.x;   // node id 0..16383
    int b = t >> 10;
    int n = t & 1023;
    int o = n >> 6;
    int base = (b << 14) + (o << 10) + ((n & 63) << 4);
    f32x4 m[4] = {{0,0,0,0},{0,0,0,0},{0,0,0,0},{0,0,0,0}};
    f32x4 lv[4] = {{0,0,0,0},{0,0,0,0},{0,0,0,0},{0,0,0,0}};
    #pragma unroll
    for (int kc = 0; kc < 8; ++kc) {
        const float* pm = pmu + (kc << 18) + base;
        const float* pl = plv + (kc << 18) + base;
        #pragma unroll
        for (int j = 0; j < 4; ++j) {
            m[j]  += *(const f32x4*)(pm + 4 * j);
            lv[j] += *(const f32x4*)(pl + 4 * j);
        }
    }
    float mb = mu_b[o], lb = lv_b[o];
    float ad = 0.f, klp = 0.f;
    #pragma unroll
    for (int j = 0; j < 4; ++j) {
        m[j]  = m[j] + mb;
        lv[j] = lv[j] + lb;
        #pragma unroll
        for (int c = 0; c < 4; ++c) {
            float mm = m[j][c], ll = lv[j][c];
            ad  += mm * mm;
            klp += 1.0f + 2.0f * ll - mm * mm - expf(2.0f * ll);
        }
        *(f32x4*)(z + t * 16 + 4 * j)     = m[j];
        *(f32x4*)(lvout + t * 16 + 4 * j) = lv[j];
    }
    ws[AD_W + t] = ad;
    float lg = logf(ad + 1e-7f);
    float sg = ad;
    #pragma unroll
    for (int off = 32; off > 0; off >>= 1) {
        sg  += __shfl_down(sg, off);
        klp += __shfl_down(klp, off);
        lg  += __shfl_down(lg, off);
    }
    __shared__ float red[3][4];
    int wv = threadIdx.x >> 6;
    if ((threadIdx.x & 63) == 0) { red[0][wv] = sg; red[1][wv] = klp; red[2][wv] = lg; }
    __syncthreads();
    if (threadIdx.x == 0) {
        ws[PART_W + blockIdx.x * 4 + 0] = red[0][0] + red[0][1] + red[0][2] + red[0][3];
        ws[PART_W + blockIdx.x * 4 + 1] = red[1][0] + red[1][1] + red[1][2] + red[1][3];
        ws[PART_W + blockIdx.x * 4 + 2] = red[2][0] + red[2][1] + red[2][2] + red[2][3];
    }
}

// ---- K3b: reduce 64 block partials -> gamma, kl_loss, dl_loss (1 wave) ----
__global__ void finalize_kernel(float* __restrict__ ws, float* __restrict__ out) {
    int t = threadIdx.x;                      // 64
    float sg = ws[PART_W + t * 4 + 0];
    float kl = ws[PART_W + t * 4 + 1];
    float lg = ws[PART_W + t * 4 + 2];
    #pragma unroll
    for (int off = 32; off > 0; off >>= 1) {
        kl += __shfl_down(kl, off);
        lg += __shfl_down(lg, off);
    }
    float kl0 = __shfl(kl, 0);
    float lg0 = __shfl(lg, 0);
    sg += __shfl_down(sg, 1);
    sg += __shfl_down(sg, 2);                 // lane 4b holds sigma[b]
    if ((t & 3) == 0) {
        int b = t >> 2;
        float g = sqrtf(1.0f + 1024.0f / (sg + 1e-7f));
        ws[GAM_W + b] = g;
        out[DLOFF + b] = -g * lg0 / 16777216.0f;
    }
    if (t == 0) out[KLOFF] = -0.5f * kl0;
}

// ---- K3c: z_hat = gamma * mu * (1 - lv), in place over lv ----
__global__ __launch_bounds__(256) void zh_kernel(const float* __restrict__ mu,
        float* __restrict__ lvzh, const float* __restrict__ gamma)
{
    int i = blockIdx.x * 256 + threadIdx.x;
    int b = i >> 12;
    float g = gamma[b];
    float4 m = ((const float4*)mu)[i];
    float4 l = ((float4*)lvzh)[i];
    float4 zh;
    zh.x = g * m.x * (1.0f - l.x);
    zh.y = g * m.y * (1.0f - l.y);
    zh.z = g * m.z * (1.0f - l.z);
    zh.w = g * m.w * (1.0f - l.w);
    ((float4*)lvzh)[i] = zh;
}

// ---- K4: deg row sums -> dis ----
__global__ __launch_bounds__(256) void deg_kernel(const float* __restrict__ z,
        float* __restrict__ ws)
{
    __shared__ float psum[16][17];
    int b  = blockIdx.x >> 6;
    int n0 = (blockIdx.x & 63) * 16;
    int t  = threadIdx.x;
    int nl = t & 15;
    int g  = t >> 4;
    const float* zb = z + (b << 14);
    const float4* a4 = (const float4*)(zb + (n0 + nl) * 16);
    float4 a0 = a4[0], a1 = a4[1], a2 = a4[2], a3 = a4[3];
    float rs = 0.f;
    const float4* m4 = (const float4*)(zb + (g << 6) * 16);
    for (int m = 0; m < 64; ++m) {
        float4 s0 = m4[m*4], s1 = m4[m*4+1], s2 = m4[m*4+2], s3 = m4[m*4+3];
        float d = a0.x*s0.x + a0.y*s0.y + a0.z*s0.z + a0.w*s0.w
                + a1.x*s1.x + a1.y*s1.y + a1.z*s1.z + a1.w*s1.w
                + a2.x*s2.x + a2.y*s2.y + a2.z*s2.z + a2.w*s2.w
                + a3.x*s3.x + a3.y*s3.y + a3.z*s3.z + a3.w*s3.w;
        rs += fmaxf(d, 0.f);
    }
    psum[g][nl] = rs;
    __syncthreads();
    if (t < 16) {
        float total = 0.f;
        #pragma unroll
        for (int gg = 0; gg < 16; ++gg) total += psum[gg][t];
        int n = n0 + t;
        float gam = ws[GAM_W + b];
        float deg = total + gam * ws[AD_W + (b << 10) + n] + 1.0f;
        ws[DIS_W + (b << 10) + n] = rsqrtf(deg + 1e-5f);
    }
}

// ---- K5: LA[b,n,m] = dis_n * dis_m * A ----
__global__ __launch_bounds__(256) void la_kernel(const float* __restrict__ z,
        const float* __restrict__ ws, float* __restrict__ LA)
{
    __shared__ float4 za[256];
    __shared__ float4 zbm[256];
    __shared__ float dan[64], dbm[64];
    int b    = blockIdx.x >> 8;
    int tile = blockIdx.x & 255;
    int n0 = (tile >> 4) * 64;
    int m0 = (tile & 15) * 64;
    int t  = threadIdx.x;
    const float4* zsrc = (const float4*)(z + (b << 14));
    za[t]  = zsrc[(n0 << 2) + t];
    zbm[t] = zsrc[(m0 << 2) + t];
    const float* dis = ws + DIS_W + (b << 10);
    if (t < 64)       dan[t]      = dis[n0 + t];
    else if (t < 128) dbm[t - 64] = dis[m0 + (t - 64)];
    __syncthreads();
    int ri = t >> 4;
    int cj = t & 15;
    float acc[4][4] = {{0.f,0.f,0.f,0.f},{0.f,0.f,0.f,0.f},
                       {0.f,0.f,0.f,0.f},{0.f,0.f,0.f,0.f}};
    #pragma unroll
    for (int kk = 0; kk < 4; ++kk) {
        float4 av[4], bv[4];
        #pragma unroll
        for (int i = 0; i < 4; ++i) av[i] = za[((ri * 4 + i) << 2) + kk];
        #pragma unroll
        for (int j = 0; j < 4; ++j) bv[j] = zbm[((cj * 4 + j) << 2) + kk];
        #pragma unroll
        for (int i = 0; i < 4; ++i)
            #pragma unroll
            for (int j = 0; j < 4; ++j)
                acc[i][j] += av[i].x * bv[j].x + av[i].y * bv[j].y
                           + av[i].z * bv[j].z + av[i].w * bv[j].w;
    }
    float g = ws[GAM_W + b];
    const float* Ad = ws + AD_W + (b << 10);
    #pragma unroll
    for (int i = 0; i < 4; ++i) {
        int n = n0 + ri * 4 + i;
        float dn = dan[ri * 4 + i];
        float4 o;
        float* op = &o.x;
        #pragma unroll
        for (int j = 0; j < 4; ++j) {
            int m = m0 + cj * 4 + j;
            float v = fmaxf(acc[i][j], 0.f);
            if (n == m) v += g * Ad[n] + 1.0f;
            op[j] = dn * dbm[cj * 4 + j] * v;
        }
        *(float4*)(LA + ((size_t)b << 20) + ((size_t)n << 10) + m0 + cj * 4) = o;
    }
}

extern "C" void kernel_launch(void* const* d_in, const int* in_sizes, int n_in,
                              void* d_out, int out_size, void* d_ws, size_t ws_size,
                              hipStream_t stream) {
    const float* feature = (const float*)d_in[0];
    const float* mu_w    = (const float*)d_in[1];
    const float* mu_b    = (const float*)d_in[2];
    const float* lv_w    = (const float*)d_in[3];
    const float* lv_b    = (const float*)d_in[4];
    float* out = (float*)d_out;
    float* ws  = (float*)d_ws;
    unsigned short* nT   = (unsigned short*)d_out;          // LA region scratch
    unsigned short* apk  = nT + APK_U;
    unsigned short* lvpk = nT + LVPK_U;

    pool_tr_kernel<<<8192, 256, 0, stream>>>(feature, nT);
    prep_kernel<<<640, 256, 0, stream>>>(mu_w, lv_w, apk, lvpk);
    conv_mfma<<<2048, 256, 0, stream>>>(nT, apk, lvpk, ws + PMU_W, ws + PLV_W);
    stats_kernel<<<64, 256, 0, stream>>>(ws + PMU_W, ws + PLV_W, mu_b, lv_b,
                                         out + ZOFF, out + ZHOFF, ws);
    finalize_kernel<<<1, 64, 0, stream>>>(ws, out);
    zh_kernel<<<256, 256, 0, stream>>>(out + ZOFF, out + ZHOFF, ws + GAM_W);
    deg_kernel<<<1024, 256, 0, stream>>>(out + ZOFF, ws);
    la_kernel<<<4096, 256, 0, stream>>>(out + ZOFF, ws, out);
}

// Round 5
// 139.788 us; speedup vs baseline: 5.0593x; 1.2054x over previous
//
#include <hip/hip_runtime.h>

typedef short short8 __attribute__((ext_vector_type(8)));
typedef float f32x4 __attribute__((ext_vector_type(4)));

// ---- problem constants ----
// B=16, C=1024, H=W=64, nodes 32x32, N=1024, HID=16
// d_out float offsets
#define ZOFF   16777216   // z   (B*N*HID = 262144)  == mu flat (with bias)
#define ZHOFF  17039360   // z_hat (262144)          == log_var temp, then z_hat
#define KLOFF  17301504   // kl scalar
#define DLOFF  17301505   // dl (16)
// d_out ushort offsets (scratch inside LA region, dead before la_kernel)
#define NT_U   0          // nodesT bf16 [16][1024][1024]
#define APK_U  16777216   // Apk bf16 [9][32][64][8] = 147,456
#define LVPK_U 16924672   // lvpk bf16 [32][64][8] = 16,384
// ws float offsets
#define AD_W   0          // Ad[B*N] = 16384
#define DIS_W  16384      // dis[B*N]
#define PART_W 32768      // 64 blocks x 4 floats: sigma,kl,lg partials
#define GAM_W  33024      // gamma[16]
#define PMU_W  65536      // mu partials [8][16][16][1024]
#define PLV_W  2162688    // lv partials, same shape

__device__ __forceinline__ unsigned short f2bf(float f) {
    unsigned int u = __float_as_uint(f);
    unsigned int r = (u + 0x7fffu + ((u >> 16) & 1u)) >> 16;
    return (unsigned short)r;
}

// ---- K1: fused 2x2 mean pool + transpose (+ weight prep in blocks <640) ----
__global__ __launch_bounds__(256) void pool_tr_kernel(const float* __restrict__ f,
        unsigned short* __restrict__ nT, const float* __restrict__ mu_w,
        const float* __restrict__ lv_w, unsigned short* __restrict__ apk,
        unsigned short* __restrict__ lvpk)
{
    __shared__ float pl[64][35];
    int blk = blockIdx.x;
    int b  = blk >> 9;
    int y  = (blk >> 4) & 31;
    int cb = blk & 15;
    int t  = threadIdx.x;
    int cl = t >> 2, q2 = t & 3;
    int c  = (cb << 6) + cl;
    float acc[8] = {0.f,0.f,0.f,0.f,0.f,0.f,0.f,0.f};
    #pragma unroll
    for (int rr = 0; rr < 2; ++rr) {
        const float4* src = (const float4*)f
            + ((((b << 10) + c) << 6) + (y << 1) + rr) * 16 + (q2 << 2);
        #pragma unroll
        for (int m = 0; m < 4; ++m) {
            float4 v = src[m];
            acc[2*m]   += v.x + v.y;
            acc[2*m+1] += v.z + v.w;
        }
    }
    #pragma unroll
    for (int i = 0; i < 8; ++i) pl[cl][(q2 << 3) + i] = 0.25f * acc[i];
    __syncthreads();
    int px = t >> 3, cj = (t & 7) << 3;
    unsigned short o8[8];
    #pragma unroll
    for (int i = 0; i < 8; ++i) o8[i] = f2bf(pl[cj + i][px]);
    int ofs = (((b << 10) + (y << 5) + px) << 10) + (cb << 6) + cj;
    *(short8*)&nT[ofs] = *(short8*)o8;

    // fused weight prep (640 blocks x 256 threads covers 163840 elems)
    if (blk < 640) {
        int idx = blk * 256 + t;
        if (idx < 147456) {
            int tap = idx >> 14;
            int rem = idx & 16383;
            int ks = rem >> 9;
            int lane = (rem >> 3) & 63;
            int j = idx & 7;
            int o = lane & 15;
            int cc = (ks << 5) + ((lane >> 4) << 3) + j;
            apk[idx] = f2bf(mu_w[((o << 10) + cc) * 9 + tap]);
        } else {
            int i2 = idx - 147456;
            int ks = i2 >> 9;
            int lane = (i2 >> 3) & 63;
            int j = i2 & 7;
            int o = lane & 15;
            int cc = (ks << 5) + ((lane >> 4) << 3) + j;
            lvpk[i2] = f2bf(lv_w[(o << 10) + cc]);
        }
    }
}

// ---- K2: MFMA conv split-K partials: mu (3x3 SAME) + lv (1x1) --------------
// grid 1024 = b(16) x ytile(8: 4 rows) x kchunk(8: 128 ch); block 256 = 4 waves
// wave w owns output row y0+w (32 positions = 2 halves). LDS ch-dim padded 40.
__global__ __launch_bounds__(256) void conv_mfma(const unsigned short* __restrict__ nT,
        const unsigned short* __restrict__ apk, const unsigned short* __restrict__ lvpk,
        float* __restrict__ pmu, float* __restrict__ plv)
{
    __shared__ unsigned short st[6 * 34 * 40];   // 16320 B, stride 80B = 5 quads
    int blk = blockIdx.x;
    int b  = blk >> 6;
    int yt = (blk >> 3) & 7;
    int kc = blk & 7;
    int y0 = yt << 2;
    int t  = threadIdx.x;
    int w  = t >> 6, l = t & 63;
    int px = l & 15, chg = l >> 4;
    f32x4 accm[2] = {{0,0,0,0},{0,0,0,0}};
    f32x4 accv[2] = {{0,0,0,0},{0,0,0,0}};

    if (t < 48) {                                 // x-halo zeros: 6 rows x 2 x 4
        int row = t >> 3, side = (t >> 2) & 1, quarter = t & 3;
        short8 z8 = {0,0,0,0,0,0,0,0};
        *(short8*)&st[(row * 34 + side * 33) * 40 + quarter * 8] = z8;
    }

    for (int s = 0; s < 4; ++s) {
        int ksg = (kc << 2) + s;                  // global k-step 0..31
        int cs  = ksg << 5;
        __syncthreads();
        #pragma unroll
        for (int k2 = 0; k2 < 3; ++k2) {          // stage 6 rows x 32 x x 32 ch
            int q = t + (k2 << 8);
            int quarter = q & 3, x = (q >> 2) & 31, row = q >> 7;
            int yin = y0 - 1 + row;
            short8 v = {0,0,0,0,0,0,0,0};
            if (yin >= 0 && yin < 32)
                v = *(const short8*)&nT[(((b << 10) + (yin << 5) + x) << 10) + cs + quarter * 8];
            *(short8*)&st[(row * 34 + x + 1) * 40 + quarter * 8] = v;
        }
        __syncthreads();
        short8 bw[9], bvw;
        #pragma unroll
        for (int tap = 0; tap < 9; ++tap)
            bw[tap] = *(const short8*)&apk[((tap << 5) + ksg) * 512 + l * 8];
        bvw = *(const short8*)&lvpk[(ksg << 9) + l * 8];
        #pragma unroll
        for (int h = 0; h < 2; ++h) {
            short8 actr;
            #pragma unroll
            for (int ky = 0; ky < 3; ++ky) {
                int row = w + ky;
                #pragma unroll
                for (int kx = 0; kx < 3; ++kx) {
                    int xx = (h << 4) + px + kx;
                    short8 a = *(const short8*)&st[(row * 34 + xx) * 40 + chg * 8];
                    if (ky == 1 && kx == 1) actr = a;
                    accm[h] = __builtin_amdgcn_mfma_f32_16x16x32_bf16(a, bw[ky*3+kx], accm[h], 0, 0, 0);
                }
            }
            accv[h] = __builtin_amdgcn_mfma_f32_16x16x32_bf16(actr, bvw, accv[h], 0, 0, 0);
        }
    }
    // D: lane holds D[pos=(l>>4)*4+j][o=l&15]
    int o = px;
    #pragma unroll
    for (int h = 0; h < 2; ++h) {
        int x = (h << 4) + (chg << 2);
        int idx = (((kc << 4) + b) << 14) + (o << 10) + ((y0 + w) << 5) + x;
        *(f32x4*)&pmu[idx] = accm[h];
        *(f32x4*)&plv[idx] = accv[h];
    }
}

// ---- K3: combine split-K + bias -> z/lv outputs; Ad, block partials --------
__global__ __launch_bounds__(256) void stats_kernel(const float* __restrict__ pmu,
        const float* __restrict__ plv, const float* __restrict__ mu_b,
        const float* __restrict__ lv_b, float* __restrict__ z,
        float* __restrict__ lvout, float* __restrict__ ws)
{
    int t = blockIdx.x * 256 + threadIdx.x;   // node id 0..16383
    int b = t >> 10;
    int n = t & 1023;
    int o = n >> 6;
    int base = (b << 14) + (o << 10) + ((n & 63) << 4);
    f32x4 m[4] = {{0,0,0,0},{0,0,0,0},{0,0,0,0},{0,0,0,0}};
    f32x4 lv[4] = {{0,0,0,0},{0,0,0,0},{0,0,0,0},{0,0,0,0}};
    #pragma unroll
    for (int kc = 0; kc < 8; ++kc) {
        const float* pm = pmu + (kc << 18) + base;
        const float* pl = plv + (kc << 18) + base;
        #pragma unroll
        for (int j = 0; j < 4; ++j) {
            m[j]  += *(const f32x4*)(pm + 4 * j);
            lv[j] += *(const f32x4*)(pl + 4 * j);
        }
    }
    float mb = mu_b[o], lb = lv_b[o];
    float ad = 0.f, klp = 0.f;
    #pragma unroll
    for (int j = 0; j < 4; ++j) {
        m[j]  = m[j] + mb;
        lv[j] = lv[j] + lb;
        #pragma unroll
        for (int c = 0; c < 4; ++c) {
            float mm = m[j][c], ll = lv[j][c];
            ad  += mm * mm;
            klp += 1.0f + 2.0f * ll - mm * mm - expf(2.0f * ll);
        }
        *(f32x4*)(z + t * 16 + 4 * j)     = m[j];
        *(f32x4*)(lvout + t * 16 + 4 * j) = lv[j];
    }
    ws[AD_W + t] = ad;
    float lg = logf(ad + 1e-7f);
    float sg = ad;
    #pragma unroll
    for (int off = 32; off > 0; off >>= 1) {
        sg  += __shfl_down(sg, off);
        klp += __shfl_down(klp, off);
        lg  += __shfl_down(lg, off);
    }
    __shared__ float red[3][4];
    int wv = threadIdx.x >> 6;
    if ((threadIdx.x & 63) == 0) { red[0][wv] = sg; red[1][wv] = klp; red[2][wv] = lg; }
    __syncthreads();
    if (threadIdx.x == 0) {
        ws[PART_W + blockIdx.x * 4 + 0] = red[0][0] + red[0][1] + red[0][2] + red[0][3];
        ws[PART_W + blockIdx.x * 4 + 1] = red[1][0] + red[1][1] + red[1][2] + red[1][3];
        ws[PART_W + blockIdx.x * 4 + 2] = red[2][0] + red[2][1] + red[2][2] + red[2][3];
    }
}

// ---- K4: deg row sums -> dis; fused gamma / z_hat / kl / dl ----------------
// grid 1024 = b(16) x ntile(64: 16 n); block 256 = 16 n x 16 m-groups
__global__ __launch_bounds__(256) void deg_kernel(const float* __restrict__ z,
        float* __restrict__ lvzh, float* __restrict__ ws, float* __restrict__ out)
{
    __shared__ float psum[16][17];
    int b  = blockIdx.x >> 6;
    int n0 = (blockIdx.x & 63) * 16;
    int t  = threadIdx.x;
    int nl = t & 15;
    int mg = t >> 4;
    float sg4 = ws[PART_W + ((b << 2) + 0) * 4] + ws[PART_W + ((b << 2) + 1) * 4]
              + ws[PART_W + ((b << 2) + 2) * 4] + ws[PART_W + ((b << 2) + 3) * 4];
    float gam = sqrtf(1.0f + 1024.0f / (sg4 + 1e-7f));
    const float* zb = z + (b << 14);
    const float4* a4 = (const float4*)(zb + (n0 + nl) * 16);
    float4 a0 = a4[0], a1 = a4[1], a2 = a4[2], a3 = a4[3];
    float rs = 0.f;
    const float4* m4 = (const float4*)(zb + (mg << 6) * 16);
    for (int m = 0; m < 64; ++m) {
        float4 s0 = m4[m*4], s1 = m4[m*4+1], s2 = m4[m*4+2], s3 = m4[m*4+3];
        float d = a0.x*s0.x + a0.y*s0.y + a0.z*s0.z + a0.w*s0.w
                + a1.x*s1.x + a1.y*s1.y + a1.z*s1.z + a1.w*s1.w
                + a2.x*s2.x + a2.y*s2.y + a2.z*s2.z + a2.w*s2.w
                + a3.x*s3.x + a3.y*s3.y + a3.z*s3.z + a3.w*s3.w;
        rs += fmaxf(d, 0.f);
    }
    psum[mg][nl] = rs;
    __syncthreads();
    if (t < 16) {
        float total = 0.f;
        #pragma unroll
        for (int gg = 0; gg < 16; ++gg) total += psum[gg][t];
        int n = n0 + t;
        float deg = total + gam * ws[AD_W + (b << 10) + n] + 1.0f;
        ws[DIS_W + (b << 10) + n] = rsqrtf(deg + 1e-5f);
    }
    // fused z_hat for rows n0..n0+15 (1 elem/thread)
    int zi = (b << 14) + ((n0 + (t >> 4)) << 4) + (t & 15);
    lvzh[zi] = gam * z[zi] * (1.0f - lvzh[zi]);
    // block 0: global reductions -> kl, dl, gamma table
    if (blockIdx.x == 0 && t < 64) {
        float kl = ws[PART_W + t * 4 + 1];
        float lg = ws[PART_W + t * 4 + 2];
        #pragma unroll
        for (int off = 32; off > 0; off >>= 1) {
            kl += __shfl_down(kl, off);
            lg += __shfl_down(lg, off);
        }
        float kl0 = __shfl(kl, 0);
        float lg0 = __shfl(lg, 0);
        if (t < 16) {
            float s = ws[PART_W + ((t << 2) + 0) * 4] + ws[PART_W + ((t << 2) + 1) * 4]
                    + ws[PART_W + ((t << 2) + 2) * 4] + ws[PART_W + ((t << 2) + 3) * 4];
            float g = sqrtf(1.0f + 1024.0f / (s + 1e-7f));
            ws[GAM_W + t] = g;
            out[DLOFF + t] = -g * lg0 / 16777216.0f;
        }
        if (t == 0) out[KLOFF] = -0.5f * kl0;
    }
}

// ---- K5: LA[b,n,m] = dis_n * dis_m * A  (grouped-LDS, conflict-free) -------
__global__ __launch_bounds__(256) void la_kernel(const float* __restrict__ z,
        const float* __restrict__ ws, float* __restrict__ LA)
{
    __shared__ float4 za_s[256];   // [jj][kk][slot16]: row = 4*slot + jj
    __shared__ float4 zbm_s[256];
    __shared__ float dan[64], dbm[64];
    int b    = blockIdx.x >> 8;
    int tile = blockIdx.x & 255;
    int n0 = (tile >> 4) * 64;
    int m0 = (tile & 15) * 64;
    int t  = threadIdx.x;
    const float4* zsrc = (const float4*)(z + (b << 14));
    {
        int slot = t & 15, kk = (t >> 4) & 3, jj = t >> 6;
        int rn = n0 + (slot << 2) + jj;
        int rm = m0 + (slot << 2) + jj;
        za_s[t]  = zsrc[(rn << 2) + kk];
        zbm_s[t] = zsrc[(rm << 2) + kk];
    }
    const float* dis = ws + DIS_W + (b << 10);
    if (t < 64)       dan[t]      = dis[n0 + t];
    else if (t < 128) dbm[t - 64] = dis[m0 + (t - 64)];
    __syncthreads();
    int ri = t >> 4;
    int cj = t & 15;
    float acc[4][4] = {{0.f,0.f,0.f,0.f},{0.f,0.f,0.f,0.f},
                       {0.f,0.f,0.f,0.f},{0.f,0.f,0.f,0.f}};
    #pragma unroll
    for (int kk = 0; kk < 4; ++kk) {
        float4 av[4], bv[4];
        #pragma unroll
        for (int i = 0; i < 4; ++i) av[i] = za_s[(((i << 2) + kk) << 4) + ri];
        #pragma unroll
        for (int j = 0; j < 4; ++j) bv[j] = zbm_s[(((j << 2) + kk) << 4) + cj];
        #pragma unroll
        for (int i = 0; i < 4; ++i)
            #pragma unroll
            for (int j = 0; j < 4; ++j)
                acc[i][j] += av[i].x * bv[j].x + av[i].y * bv[j].y
                           + av[i].z * bv[j].z + av[i].w * bv[j].w;
    }
    float g = ws[GAM_W + b];
    const float* Ad = ws + AD_W + (b << 10);
    #pragma unroll
    for (int i = 0; i < 4; ++i) {
        int n = n0 + ri * 4 + i;
        float dn = dan[ri * 4 + i];
        float4 o;
        float* op = &o.x;
        #pragma unroll
        for (int j = 0; j < 4; ++j) {
            int m = m0 + cj * 4 + j;
            float v = fmaxf(acc[i][j], 0.f);
            if (n == m) v += g * Ad[n] + 1.0f;
            op[j] = dn * dbm[cj * 4 + j] * v;
        }
        *(float4*)(LA + ((size_t)b << 20) + ((size_t)n << 10) + m0 + cj * 4) = o;
    }
}

extern "C" void kernel_launch(void* const* d_in, const int* in_sizes, int n_in,
                              void* d_out, int out_size, void* d_ws, size_t ws_size,
                              hipStream_t stream) {
    const float* feature = (const float*)d_in[0];
    const float* mu_w    = (const float*)d_in[1];
    const float* mu_b    = (const float*)d_in[2];
    const float* lv_w    = (const float*)d_in[3];
    const float* lv_b    = (const float*)d_in[4];
    float* out = (float*)d_out;
    float* ws  = (float*)d_ws;
    unsigned short* nT   = (unsigned short*)d_out;          // LA region scratch
    unsigned short* apk  = nT + APK_U;
    unsigned short* lvpk = nT + LVPK_U;

    pool_tr_kernel<<<8192, 256, 0, stream>>>(feature, nT, mu_w, lv_w, apk, lvpk);
    conv_mfma<<<1024, 256, 0, stream>>>(nT, apk, lvpk, ws + PMU_W, ws + PLV_W);
    stats_kernel<<<64, 256, 0, stream>>>(ws + PMU_W, ws + PLV_W, mu_b, lv_b,
                                         out + ZOFF, out + ZHOFF, ws);
    deg_kernel<<<1024, 256, 0, stream>>>(out + ZOFF, out + ZHOFF, ws, out);
    la_kernel<<<4096, 256, 0, stream>>>(out + ZOFF, ws, out);
}

// Round 6
// 136.697 us; speedup vs baseline: 5.1737x; 1.0226x over previous
//
#include <hip/hip_runtime.h>

typedef short short8 __attribute__((ext_vector_type(8)));
typedef float f32x4 __attribute__((ext_vector_type(4)));

// ---- problem constants ----
// B=16, C=1024, H=W=64, nodes 32x32, N=1024, HID=16
// d_out float offsets
#define ZOFF   16777216   // z   (B*N*HID = 262144)  == mu flat (with bias)
#define ZHOFF  17039360   // z_hat (262144)          == log_var temp, then z_hat
#define KLOFF  17301504   // kl scalar
#define DLOFF  17301505   // dl (16)
// d_out ushort offsets (scratch inside LA region, dead before la_kernel)
#define APK_U  16777216   // Apk bf16 [9][32][64][8] = 147,456
#define LVPK_U 16924672   // lvpk bf16 [32][64][8] = 16,384
// ws float offsets
#define AD_W   0          // Ad[B*N] = 16384
#define DIS_W  16384      // dis[B*N]
#define PART_W 32768      // 256 blocks x 4 floats: sigma,kl,lg partials
#define GAM_W  34816      // gamma[16]
#define PMU_W  65536      // mu partials [8][16][16][1024]
#define PLV_W  2162688    // lv partials, same shape

__device__ __forceinline__ unsigned short f2bf(float f) {
    unsigned int u = __float_as_uint(f);
    unsigned int r = (u + 0x7fffu + ((u >> 16) & 1u)) >> 16;
    return (unsigned short)r;
}

// ---- K1: fused 2x2 mean pool + transpose (+ weight prep in blocks <640) ----
// grid 8192 = b(16) x y(32) x cb(16 of 64ch). Reads: 2x512B contiguous runs
// per instruction; vertical combine via shfl_xor(16); LDS pad-35 (<=2-way).
__global__ __launch_bounds__(256) void pool_tr_kernel(const float* __restrict__ f,
        unsigned short* __restrict__ nT, const float* __restrict__ mu_w,
        const float* __restrict__ lv_w, unsigned short* __restrict__ apk,
        unsigned short* __restrict__ lvpk)
{
    __shared__ float pls[64 * 35];
    int blk = blockIdx.x;
    int b  = blk >> 9;
    int y  = (blk >> 4) & 31;
    int cb = blk & 15;
    int t  = threadIdx.x;
    int rr  = (t >> 4) & 1;
    int c16 = t & 15;
    int cho = t >> 5;
    #pragma unroll
    for (int k = 0; k < 8; ++k) {
        int ch = (k << 3) + cho;
        float4 v = ((const float4*)f)[
            ((((b << 10) + (cb << 6) + ch) << 6) + (y << 1) + rr) * 16 + c16];
        float h0 = v.x + v.y, h1 = v.z + v.w;
        float g0 = h0 + __shfl_xor(h0, 16);
        float g1 = h1 + __shfl_xor(h1, 16);
        if (rr == 0) {
            pls[ch * 35 + (c16 << 1)]     = 0.25f * g0;
            pls[ch * 35 + (c16 << 1) + 1] = 0.25f * g1;
        }
    }
    __syncthreads();
    int px = t >> 3, cg = t & 7;
    unsigned short o8[8];
    #pragma unroll
    for (int i = 0; i < 8; ++i) o8[i] = f2bf(pls[((cg << 3) + i) * 35 + px]);
    int ofs = ((((b << 10) + (y << 5) + px)) << 10) + (cb << 6) + (cg << 3);
    *(short8*)&nT[ofs] = *(short8*)o8;

    if (blk < 640) {                          // fused weight prep
        int idx = blk * 256 + t;
        if (idx < 147456) {
            int tap = idx >> 14;
            int rem = idx & 16383;
            int ks = rem >> 9;
            int lane = (rem >> 3) & 63;
            int j = idx & 7;
            int o = lane & 15;
            int cc = (ks << 5) + ((lane >> 4) << 3) + j;
            apk[idx] = f2bf(mu_w[((o << 10) + cc) * 9 + tap]);
        } else {
            int i2 = idx - 147456;
            int ks = i2 >> 9;
            int lane = (i2 >> 3) & 63;
            int j = i2 & 7;
            int o = lane & 15;
            int cc = (ks << 5) + ((lane >> 4) << 3) + j;
            lvpk[i2] = f2bf(lv_w[(o << 10) + cc]);
        }
    }
}

// ---- K2: MFMA conv split-K partials: mu (3x3 SAME) + lv (1x1) --------------
// grid 1024 = b(16) x ytile(8: 4 rows) x kchunk(8: 128 ch); block 256 = 4 waves
__global__ __launch_bounds__(256) void conv_mfma(const unsigned short* __restrict__ nT,
        const unsigned short* __restrict__ apk, const unsigned short* __restrict__ lvpk,
        float* __restrict__ pmu, float* __restrict__ plv)
{
    __shared__ unsigned short st[6 * 34 * 40];   // stride 80B = 5 quads
    int blk = blockIdx.x;
    int b  = blk >> 6;
    int yt = (blk >> 3) & 7;
    int kc = blk & 7;
    int y0 = yt << 2;
    int t  = threadIdx.x;
    int w  = t >> 6, l = t & 63;
    int px = l & 15, chg = l >> 4;
    f32x4 accm[2] = {{0,0,0,0},{0,0,0,0}};
    f32x4 accv[2] = {{0,0,0,0},{0,0,0,0}};

    if (t < 48) {                                 // x-halo zeros: 6 rows x 2 x 4
        int row = t >> 3, side = (t >> 2) & 1, quarter = t & 3;
        short8 z8 = {0,0,0,0,0,0,0,0};
        *(short8*)&st[(row * 34 + side * 33) * 40 + quarter * 8] = z8;
    }

    for (int s = 0; s < 4; ++s) {
        int ksg = (kc << 2) + s;
        int cs  = ksg << 5;
        __syncthreads();
        #pragma unroll
        for (int k2 = 0; k2 < 3; ++k2) {          // stage 6 rows x 32 x x 32 ch
            int q = t + (k2 << 8);
            int quarter = q & 3, x = (q >> 2) & 31, row = q >> 7;
            int yin = y0 - 1 + row;
            short8 v = {0,0,0,0,0,0,0,0};
            if (yin >= 0 && yin < 32)
                v = *(const short8*)&nT[(((b << 10) + (yin << 5) + x) << 10) + cs + quarter * 8];
            *(short8*)&st[(row * 34 + x + 1) * 40 + quarter * 8] = v;
        }
        __syncthreads();
        short8 bw[9], bvw;
        #pragma unroll
        for (int tap = 0; tap < 9; ++tap)
            bw[tap] = *(const short8*)&apk[((tap << 5) + ksg) * 512 + l * 8];
        bvw = *(const short8*)&lvpk[(ksg << 9) + l * 8];
        #pragma unroll
        for (int h = 0; h < 2; ++h) {
            short8 actr;
            #pragma unroll
            for (int ky = 0; ky < 3; ++ky) {
                int row = w + ky;
                #pragma unroll
                for (int kx = 0; kx < 3; ++kx) {
                    int xx = (h << 4) + px + kx;
                    short8 a = *(const short8*)&st[(row * 34 + xx) * 40 + chg * 8];
                    if (ky == 1 && kx == 1) actr = a;
                    accm[h] = __builtin_amdgcn_mfma_f32_16x16x32_bf16(a, bw[ky*3+kx], accm[h], 0, 0, 0);
                }
            }
            accv[h] = __builtin_amdgcn_mfma_f32_16x16x32_bf16(actr, bvw, accv[h], 0, 0, 0);
        }
    }
    int o = px;
    #pragma unroll
    for (int h = 0; h < 2; ++h) {
        int x = (h << 4) + (chg << 2);
        int idx = (((kc << 4) + b) << 14) + (o << 10) + ((y0 + w) << 5) + x;
        *(f32x4*)&pmu[idx] = accm[h];
        *(f32x4*)&plv[idx] = accv[h];
    }
}

// ---- K3: combine split-K + bias -> z/lv; Ad, block partials ----------------
// grid 256 = b(16) x ng(16: 64 nodes); coalesced 256B-run reads, 1KB writes
__global__ __launch_bounds__(256) void stats_kernel(const float* __restrict__ pmu,
        const float* __restrict__ plv, const float* __restrict__ mu_b,
        const float* __restrict__ lv_b, float* __restrict__ z,
        float* __restrict__ lvout, float* __restrict__ ws)
{
    __shared__ float smu[16 * 68], slv[16 * 68];
    __shared__ float red[3][4];
    int blk = blockIdx.x;
    int b = blk >> 4, ng = blk & 15;
    int t = threadIdx.x;
    {
        int o = t >> 4, f4c = t & 15;
        int base = (b << 14) + (o << 10) + (ng << 6) + (f4c << 2);
        f32x4 m = {0,0,0,0}, lv = {0,0,0,0};
        #pragma unroll
        for (int kc = 0; kc < 8; ++kc) {
            m  += *(const f32x4*)(pmu + (kc << 18) + base);
            lv += *(const f32x4*)(plv + (kc << 18) + base);
        }
        float mb = mu_b[o], lb = lv_b[o];
        #pragma unroll
        for (int c = 0; c < 4; ++c) {
            smu[o * 68 + (f4c << 2) + c] = m[c] + mb;
            slv[o * 68 + (f4c << 2) + c] = lv[c] + lb;
        }
    }
    __syncthreads();
    int node2 = t >> 2, og = t & 3;
    f32x4 zm, zl;
    float ad = 0.f, klp = 0.f;
    #pragma unroll
    for (int c = 0; c < 4; ++c) {
        float mm = smu[((og << 2) + c) * 68 + node2];
        float ll = slv[((og << 2) + c) * 68 + node2];
        zm[c] = mm; zl[c] = ll;
        ad  += mm * mm;
        klp += 1.0f + 2.0f * ll - mm * mm - expf(2.0f * ll);
    }
    int zofs = (b << 14) + (((ng << 6) + node2) << 4) + (og << 2);
    *(f32x4*)(z + zofs)     = zm;
    *(f32x4*)(lvout + zofs) = zl;
    ad  += __shfl_xor(ad, 1);  ad  += __shfl_xor(ad, 2);
    klp += __shfl_xor(klp, 1); klp += __shfl_xor(klp, 2);
    float lg = logf(ad + 1e-7f);
    if (og == 0) ws[AD_W + (b << 10) + (ng << 6) + node2] = ad;
    float sgc = (og == 0) ? ad  : 0.f;
    float klc = (og == 0) ? klp : 0.f;
    float lgc = (og == 0) ? lg  : 0.f;
    #pragma unroll
    for (int off = 32; off > 0; off >>= 1) {
        sgc += __shfl_down(sgc, off);
        klc += __shfl_down(klc, off);
        lgc += __shfl_down(lgc, off);
    }
    int wv = t >> 6;
    if ((t & 63) == 0) { red[0][wv] = sgc; red[1][wv] = klc; red[2][wv] = lgc; }
    __syncthreads();
    if (t == 0) {
        ws[PART_W + (blk << 2) + 0] = red[0][0] + red[0][1] + red[0][2] + red[0][3];
        ws[PART_W + (blk << 2) + 1] = red[1][0] + red[1][1] + red[1][2] + red[1][3];
        ws[PART_W + (blk << 2) + 2] = red[2][0] + red[2][1] + red[2][2] + red[2][3];
    }
}

// ---- K4: deg row sums -> dis; fused gamma / z_hat / kl / dl ----------------
__global__ __launch_bounds__(256) void deg_kernel(const float* __restrict__ z,
        float* __restrict__ lvzh, float* __restrict__ ws, float* __restrict__ out)
{
    __shared__ float psum[16][17];
    __shared__ float redk[4], redl[4], fin[2];
    int b  = blockIdx.x >> 6;
    int n0 = (blockIdx.x & 63) * 16;
    int t  = threadIdx.x;
    int nl = t & 15;
    int mg = t >> 4;
    float sg16 = 0.f;
    #pragma unroll
    for (int g = 0; g < 16; ++g) sg16 += ws[PART_W + (((b << 4) + g) << 2)];
    float gam = sqrtf(1.0f + 1024.0f / (sg16 + 1e-7f));
    const float* zb = z + (b << 14);
    const float4* a4 = (const float4*)(zb + (n0 + nl) * 16);
    float4 a0 = a4[0], a1 = a4[1], a2 = a4[2], a3 = a4[3];
    float rs = 0.f;
    const float4* m4 = (const float4*)(zb + (mg << 6) * 16);
    for (int m = 0; m < 64; ++m) {
        float4 s0 = m4[m*4], s1 = m4[m*4+1], s2 = m4[m*4+2], s3 = m4[m*4+3];
        float d = a0.x*s0.x + a0.y*s0.y + a0.z*s0.z + a0.w*s0.w
                + a1.x*s1.x + a1.y*s1.y + a1.z*s1.z + a1.w*s1.w
                + a2.x*s2.x + a2.y*s2.y + a2.z*s2.z + a2.w*s2.w
                + a3.x*s3.x + a3.y*s3.y + a3.z*s3.z + a3.w*s3.w;
        rs += fmaxf(d, 0.f);
    }
    psum[mg][nl] = rs;
    __syncthreads();
    if (t < 16) {
        float total = 0.f;
        #pragma unroll
        for (int gg = 0; gg < 16; ++gg) total += psum[gg][t];
        int n = n0 + t;
        float deg = total + gam * ws[AD_W + (b << 10) + n] + 1.0f;
        ws[DIS_W + (b << 10) + n] = rsqrtf(deg + 1e-5f);
    }
    int zi = (b << 14) + ((n0 + (t >> 4)) << 4) + (t & 15);
    lvzh[zi] = gam * z[zi] * (1.0f - lvzh[zi]);
    if (blockIdx.x == 0) {
        float kl = ws[PART_W + (t << 2) + 1];
        float lg = ws[PART_W + (t << 2) + 2];
        #pragma unroll
        for (int off = 32; off > 0; off >>= 1) {
            kl += __shfl_down(kl, off);
            lg += __shfl_down(lg, off);
        }
        if ((t & 63) == 0) { redk[t >> 6] = kl; redl[t >> 6] = lg; }
        __syncthreads();
        if (t == 0) {
            fin[0] = redk[0] + redk[1] + redk[2] + redk[3];
            fin[1] = redl[0] + redl[1] + redl[2] + redl[3];
            out[KLOFF] = -0.5f * fin[0];
        }
        __syncthreads();
        if (t < 16) {
            float s = 0.f;
            #pragma unroll
            for (int g = 0; g < 16; ++g) s += ws[PART_W + (((t << 4) + g) << 2)];
            float gm = sqrtf(1.0f + 1024.0f / (s + 1e-7f));
            ws[GAM_W + t] = gm;
            out[DLOFF + t] = -gm * fin[1] / 16777216.0f;
        }
    }
}

// ---- K5: LA[b,n,m] = dis_n * dis_m * A  (contig loads, pad-17 LDS) ---------
__global__ __launch_bounds__(256) void la_kernel(const float* __restrict__ z,
        const float* __restrict__ ws, float* __restrict__ LA)
{
    __shared__ float4 za_s[16 * 17];   // [g=jj*4+kk][slot], stride 17
    __shared__ float4 zbm_s[16 * 17];
    __shared__ float dan[64], dbm[64];
    int b    = blockIdx.x >> 8;
    int tile = blockIdx.x & 255;
    int n0 = (tile >> 4) * 64;
    int m0 = (tile & 15) * 64;
    int t  = threadIdx.x;
    const float4* zsrc = (const float4*)(z + (b << 14));
    {
        int g   = (((t >> 2) & 3) << 2) + (t & 3);   // jj*4 + kk
        int slt = t >> 4;
        za_s[g * 17 + slt]  = zsrc[(n0 << 2) + t];   // 1KB contiguous load
        zbm_s[g * 17 + slt] = zsrc[(m0 << 2) + t];
    }
    const float* dis = ws + DIS_W + (b << 10);
    if (t < 64)       dan[t]      = dis[n0 + t];
    else if (t < 128) dbm[t - 64] = dis[m0 + (t - 64)];
    __syncthreads();
    int ri = t >> 4;
    int cj = t & 15;
    float acc[4][4] = {{0.f,0.f,0.f,0.f},{0.f,0.f,0.f,0.f},
                       {0.f,0.f,0.f,0.f},{0.f,0.f,0.f,0.f}};
    #pragma unroll
    for (int kk = 0; kk < 4; ++kk) {
        float4 av[4], bv[4];
        #pragma unroll
        for (int i = 0; i < 4; ++i) av[i] = za_s[((i << 2) + kk) * 17 + ri];
        #pragma unroll
        for (int j = 0; j < 4; ++j) bv[j] = zbm_s[((j << 2) + kk) * 17 + cj];
        #pragma unroll
        for (int i = 0; i < 4; ++i)
            #pragma unroll
            for (int j = 0; j < 4; ++j)
                acc[i][j] += av[i].x * bv[j].x + av[i].y * bv[j].y
                           + av[i].z * bv[j].z + av[i].w * bv[j].w;
    }
    float g = ws[GAM_W + b];
    const float* Ad = ws + AD_W + (b << 10);
    #pragma unroll
    for (int i = 0; i < 4; ++i) {
        int n = n0 + ri * 4 + i;
        float dn = dan[ri * 4 + i];
        float4 o;
        float* op = &o.x;
        #pragma unroll
        for (int j = 0; j < 4; ++j) {
            int m = m0 + cj * 4 + j;
            float v = fmaxf(acc[i][j], 0.f);
            if (n == m) v += g * Ad[n] + 1.0f;
            op[j] = dn * dbm[cj * 4 + j] * v;
        }
        *(float4*)(LA + ((size_t)b << 20) + ((size_t)n << 10) + m0 + cj * 4) = o;
    }
}

extern "C" void kernel_launch(void* const* d_in, const int* in_sizes, int n_in,
                              void* d_out, int out_size, void* d_ws, size_t ws_size,
                              hipStream_t stream) {
    const float* feature = (const float*)d_in[0];
    const float* mu_w    = (const float*)d_in[1];
    const float* mu_b    = (const float*)d_in[2];
    const float* lv_w    = (const float*)d_in[3];
    const float* lv_b    = (const float*)d_in[4];
    float* out = (float*)d_out;
    float* ws  = (float*)d_ws;
    unsigned short* nT   = (unsigned short*)d_out;          // LA region scratch
    unsigned short* apk  = nT + APK_U;
    unsigned short* lvpk = nT + LVPK_U;

    pool_tr_kernel<<<8192, 256, 0, stream>>>(feature, nT, mu_w, lv_w, apk, lvpk);
    conv_mfma<<<1024, 256, 0, stream>>>(nT, apk, lvpk, ws + PMU_W, ws + PLV_W);
    stats_kernel<<<256, 256, 0, stream>>>(ws + PMU_W, ws + PLV_W, mu_b, lv_b,
                                          out + ZOFF, out + ZHOFF, ws);
    deg_kernel<<<1024, 256, 0, stream>>>(out + ZOFF, out + ZHOFF, ws, out);
    la_kernel<<<4096, 256, 0, stream>>>(out + ZOFF, ws, out);
}